// Round 10
// baseline (2542.280 us; speedup 1.0000x reference)
//
#include <hip/hip_runtime.h>
#include <hip/hip_fp16.h>

#define LDIM 50
#define MBIN 262144
#define ODIM 155
#define VOCABSZ 100

// ---- workspace layout (produced by precompute_kernel) ----
// half-indexed (from (__half*)ws):
#define H_T   0        // 30000 halves : T[s][v][d] fp16 (s=0 pe-slot, b_pred folded; s=1..5 ve)
#define H_VE  30000    // 5000 halves  : ve fp16   (staged to LDS)
#define H_PE  35000    // 5000 halves  : pe fp16   (read from GLOBAL, L2-hot)
// float-indexed:
#define F_LG  20000    // 300  : attention logits fp32
#define F_TB  20304    // 5000 : (oe @ W_bin[50:100] + b_bin) fp32 (global, L2-hot)

// ---- static LDS (floats): 19968 = 79872 B -> 2 blocks/CU target ----
// phase A: halves [0..35000) = T|ve (17500 fl); lg at fl [17500..17800)
// lred  fl [17800..18824) : logit partials (2 arrays x 2 pi x 256)  (dead early)
// phase B (tables dead): stA h2[0..6400) = fl [0..6400)  (hA -> h_bin -> h_q)
//                        stB h2[6400..12800) = fl [6400..12800) (hB -> h_un)
// sw    fl [12800..19968) : 8 waves x 64 x 14 store-transpose (overlays lred)
#define O_LG_LDS 17500
#define O_LRED   17800
#define O_SW     12800
#define LDS_FLOATS 19968

// ---------------------------------------------------------------------------
// Precompute vocab-indexed tables (trivial cost)
// ---------------------------------------------------------------------------
__global__ __launch_bounds__(64) void precompute_kernel(
    const float* __restrict__ pe, const float* __restrict__ ve, const float* __restrict__ oe,
    const float* __restrict__ W_pred, const float* __restrict__ b_pred,
    const float* __restrict__ W_bin, const float* __restrict__ b_bin,
    const float* __restrict__ W_att, const float* __restrict__ b_att,
    float* __restrict__ ws)
{
    __half* wsh = (__half*)ws;
    const int bid = blockIdx.x;
    const int t = threadIdx.x;
    if (bid < 600) {                    // T tables (fp16)
        const int s = bid / VOCABSZ, v = bid % VOCABSZ;
        if (t < LDIM) {
            const float* E = (s == 0) ? pe : ve;
            float acc = (s == 0) ? b_pred[t] : 0.0f;
            for (int e = 0; e < LDIM; ++e)
                acc += E[v*LDIM + e] * W_pred[(s*LDIM + e)*LDIM + t];
            wsh[H_T + (s*VOCABSZ + v)*LDIM + t] = __float2half_rn(acc);
        }
    } else if (bid < 700) {             // Tb fp32
        const int v = bid - 600;
        if (t < LDIM) {
            float acc = b_bin[t];
            for (int e = 0; e < LDIM; ++e)
                acc += oe[v*LDIM + e] * W_bin[(LDIM + e)*LDIM + t];
            ws[F_TB + v*LDIM + t] = acc;
        }
    } else if (bid < 800) {             // ve -> fp16
        const int v = bid - 700;
        if (t < LDIM) wsh[H_VE + v*LDIM + t] = __float2half_rn(ve[v*LDIM + t]);
    } else if (bid < 900) {             // pe -> fp16 (global-read table)
        const int v = bid - 800;
        if (t < LDIM) wsh[H_PE + v*LDIM + t] = __float2half_rn(pe[v*LDIM + t]);
    } else {                            // attention logits fp32
        const int g = (bid - 900)*64 + t;
        if (g < 300) {
            const int which = g / VOCABSZ, v = g % VOCABSZ;
            const float* E = (which == 0) ? pe : ((which == 1) ? ve : oe);
            float acc = b_att[0];
            for (int e = 0; e < LDIM; ++e)
                acc += E[v*LDIM + e] * W_att[e];
            ws[F_LG + g] = acc;
        }
    }
}

// ---------------------------------------------------------------------------
// h pair (dims 2i,2i+1) of a predicate node: T,ve from LDS; pe from global L2
// ---------------------------------------------------------------------------
__device__ __forceinline__ float2 node_h_i(
    int i, int p, const int* __restrict__ v,
    float e0, const float* __restrict__ ek, float inv,
    const __half* __restrict__ ldsh, const __half2* __restrict__ peg)
{
    const __half2* T2  = (const __half2*)(ldsh + H_T);
    const __half2* ve2 = (const __half2*)(ldsh + H_VE);
    float2 lin = __half22float2(T2[p*(LDIM/2) + i]);
    float2 pv  = __half22float2(peg[p*(LDIM/2) + i]);     // global, L2-hot
    float nx = e0*pv.x, ny = e0*pv.y;
#pragma unroll
    for (int s = 0; s < 5; ++s) {
        float2 a = __half22float2(T2[((s+1)*VOCABSZ + v[s])*(LDIM/2) + i]);
        float2 b = __half22float2(ve2[v[s]*(LDIM/2) + i]);
        lin.x += a.x; lin.y += a.y;
        nx += ek[s]*b.x; ny += ek[s]*b.y;
    }
    return make_float2(fmaxf(lin.x, 0.0f) + nx*inv,
                       fmaxf(lin.y, 0.0f) + ny*inv);
}

// ---------------------------------------------------------------------------
// Per-wave work, PI = wave parity: dims [26*PI, 26*PI + 26-2*PI)
// ---------------------------------------------------------------------------
template<int PI>
__device__ __forceinline__ void work(
    int nl, int lane, int wave, int pairid, int blockbase,
    int pA, int pB, const int* __restrict__ vA, const int* __restrict__ vB, int op,
    float e0A, float e0B, const float* __restrict__ ekA, const float* __restrict__ ekB,
    float invA, float invB, float w1, float batt,
    float* __restrict__ ldsf, const __half* __restrict__ ldsh,
    const __half2* __restrict__ peg,
    const float* __restrict__ oe,
    const float* __restrict__ W_bin, const float* __restrict__ W_un,
    const float* __restrict__ b_un, const float* __restrict__ W_univ,
    const float* __restrict__ b_univ, const float* __restrict__ W_att,
    const float* __restrict__ W_fin, const float* __restrict__ b_fin,
    const float* __restrict__ ws, float* __restrict__ out)
{
    constexpr int NI   = 13 - PI;    // PI=0: 13 pairs (dims 0..25), PI=1: 12 (26..49)
    constexpr int IOFF = 13 * PI;
    constexpr int DOFF = 26 * PI;

    // ---- build own dim-range of hA,hB (fp16 regs) + logit partials ----
    __half2 hA2[NI], hB2[NI];
    float lApart = (PI == 0) ? batt : 0.0f;
    float lBpart = (PI == 0) ? batt : 0.0f;
#pragma unroll
    for (int ii = 0; ii < NI; ++ii) {
        const int i = ii + IOFF;
        float2 a = node_h_i(i, pA, vA, e0A, ekA, invA, ldsh, peg);
        float2 b = node_h_i(i, pB, vB, e0B, ekB, invB, ldsh, peg);
        hA2[ii] = __floats2half2_rn(a.x, a.y);
        hB2[ii] = __floats2half2_rn(b.x, b.y);
        lApart += a.x*W_att[2*i] + a.y*W_att[2*i+1];
        lBpart += b.x*W_att[2*i] + b.y*W_att[2*i+1];
    }
    ldsf[O_LRED + PI*256 + nl]       = lApart;
    ldsf[O_LRED + 512 + PI*256 + nl] = lBpart;
    __syncthreads();                       // B2: builds done -> tables dead

    const float lA = lApart + ldsf[O_LRED + (1-PI)*256 + nl];
    const float lB = lBpart + ldsf[O_LRED + 512 + (1-PI)*256 + nl];
    const float w0 = __expf(lA), w2 = __expf(lB);
    const float inv2 = 1.0f / (w0 + w1 + w2);

    // ---- stash hA,hB fp16 over dead table region ----
    __half2* stA = reinterpret_cast<__half2*>(ldsf);   // h2 [0..6400)
    __half2* stB = stA + 6400;                         // h2 [6400..12800)
#pragma unroll
    for (int ii = 0; ii < NI; ++ii) {
        stA[nl*25 + IOFF + ii] = hA2[ii];
        stB[nl*25 + IOFF + ii] = hB2[ii];
    }
    __syncthreads();                       // B3: full hA/hB visible

    // ---- pass 2: lin2(own dims) = hA @ Wbin[0:50] + hB @ Wbin[100:150] ----
    float lin2[2*NI];
#pragma unroll
    for (int ii = 0; ii < 2*NI; ++ii) lin2[ii] = 0.0f;
    {
        const float* Wb = W_bin + DOFF;
#pragma unroll
        for (int ie = 0; ie < 25; ++ie) {
            const float2 ha = __half22float2(stA[nl*25 + ie]);
            const float2 hb = __half22float2(stB[nl*25 + ie]);
            const float* wa0 = Wb + (2*ie)*LDIM;
            const float* wa1 = wa0 + LDIM;
            const float* wb0 = Wb + (2*LDIM + 2*ie)*LDIM;
            const float* wb1 = wb0 + LDIM;
#pragma unroll
            for (int ii = 0; ii < 2*NI; ++ii)
                lin2[ii] += ha.x*wa0[ii] + ha.y*wa1[ii] + hb.x*wb0[ii] + hb.y*wb1[ii];
        }
    }

    // ---- h_bin(own): relu(lin2+Tb[op]) + (w0*hA + w2*hB + w1*oe[op])*inv2 ----
    __half2 h2o[NI];
    {
        const float2* Tb2 = (const float2*)(ws + F_TB + op*LDIM + DOFF);
        const float2* oe2 = (const float2*)(oe + op*LDIM + DOFF);
#pragma unroll
        for (int ii = 0; ii < NI; ++ii) {
            const float2 t = Tb2[ii], o = oe2[ii];
            const float2 a = __half22float2(hA2[ii]);
            const float2 b = __half22float2(hB2[ii]);
            const float hx = fmaxf(lin2[2*ii]   + t.x, 0.0f) + (w0*a.x + w2*b.x + w1*o.x)*inv2;
            const float hy = fmaxf(lin2[2*ii+1] + t.y, 0.0f) + (w0*a.y + w2*b.y + w1*o.y)*inv2;
            h2o[ii] = __floats2half2_rn(hx, hy);
        }
    }
    __syncthreads();                       // B4: all pass-2 stash reads done
#pragma unroll
    for (int ii = 0; ii < NI; ++ii) stA[nl*25 + IOFF + ii] = h2o[ii];   // h_bin -> stA
    __syncthreads();                       // B5

    // ---- h_un(own) = relu(h_bin @ W_un + b_un) ----
    {
        float acc[2*NI];
        const float* bu = b_un + DOFF;
#pragma unroll
        for (int ii = 0; ii < 2*NI; ++ii) acc[ii] = bu[ii];
        const float* Wu = W_un + DOFF;
#pragma unroll
        for (int ie = 0; ie < 25; ++ie) {
            const float2 h = __half22float2(stA[nl*25 + ie]);
            const float* wr0 = Wu + (2*ie)*LDIM;
            const float* wr1 = wr0 + LDIM;
#pragma unroll
            for (int ii = 0; ii < 2*NI; ++ii)
                acc[ii] += h.x*wr0[ii] + h.y*wr1[ii];
        }
#pragma unroll
        for (int ii = 0; ii < NI; ++ii)
            h2o[ii] = __floats2half2_rn(fmaxf(acc[2*ii], 0.0f), fmaxf(acc[2*ii+1], 0.0f));
    }
#pragma unroll
    for (int ii = 0; ii < NI; ++ii) stB[nl*25 + IOFF + ii] = h2o[ii];   // h_un -> stB
    __syncthreads();                       // B6: h_un visible; stA reads done

    // ---- h_q(own) = relu(h_un @ W_univ + b_univ) ----
    {
        float acc[2*NI];
        const float* bv = b_univ + DOFF;
#pragma unroll
        for (int ii = 0; ii < 2*NI; ++ii) acc[ii] = bv[ii];
        const float* Wv = W_univ + DOFF;
#pragma unroll
        for (int ie = 0; ie < 25; ++ie) {
            const float2 h = __half22float2(stB[nl*25 + ie]);
            const float* wr0 = Wv + (2*ie)*LDIM;
            const float* wr1 = wr0 + LDIM;
#pragma unroll
            for (int ii = 0; ii < 2*NI; ++ii)
                acc[ii] += h.x*wr0[ii] + h.y*wr1[ii];
        }
#pragma unroll
        for (int ii = 0; ii < NI; ++ii)
            h2o[ii] = __floats2half2_rn(fmaxf(acc[2*ii], 0.0f), fmaxf(acc[2*ii+1], 0.0f));
    }
#pragma unroll
    for (int ii = 0; ii < NI; ++ii) stA[nl*25 + IOFF + ii] = h2o[ii];   // h_q -> stA
    __syncthreads();                       // B7: full h_q visible

    // ---- W_fin: own 6 col-chunks of 13 (PI=0: 0..77, PI=1: 78..154) ----
    __half2 hq2[25];
#pragma unroll
    for (int ie = 0; ie < 25; ++ie) hq2[ie] = stA[nl*25 + ie];
    float* sw = ldsf + O_SW + wave*896;                 // [64][14] per wave
    float* gbase = out + (size_t)(blockbase + pairid*64) * ODIM;
#pragma unroll
    for (int cl = 0; cl < 6; ++cl) {
        const int cg = 6*PI + cl;
        const int colbase = 13*cg;
        const int NC = (cg == 11) ? 12 : 13;
        float acc[13];
#pragma unroll
        for (int o = 0; o < 13; ++o) if (o < NC) acc[o] = b_fin[colbase + o];
#pragma unroll
        for (int ie = 0; ie < 25; ++ie) {
            const float2 h = __half22float2(hq2[ie]);
            const float* wr0 = W_fin + (2*ie)*ODIM + colbase;
            const float* wr1 = wr0 + ODIM;
#pragma unroll
            for (int o = 0; o < 13; ++o) if (o < NC)
                acc[o] += h.x*wr0[o] + h.y*wr1[o];
        }
#pragma unroll
        for (int o = 0; o < 13; ++o) if (o < NC) sw[lane*14 + o] = acc[o];
        float* gb = gbase + colbase;
#pragma unroll
        for (int it = 0; it < 13; ++it) if (it < NC) {
            const int f = it*64 + lane;
            const int row = f / NC;
            const int col = f - row*NC;
            gb[row*ODIM + col] = sw[row*14 + col];
        }
    }
}

// ---------------------------------------------------------------------------
// Fused kernel: 512-thr (128-VGPR allocator regime), 4 wave-pairs x 64 nodes.
// Dim-split (live ~60-85 -> spill-free at 128) + 79872 B LDS -> 2 blocks/CU.
// ---------------------------------------------------------------------------
__global__ __launch_bounds__(512)
void fused_kernel(
    const float* __restrict__ oe,
    const float* __restrict__ W_bin,
    const float* __restrict__ W_un, const float* __restrict__ b_un,
    const float* __restrict__ W_univ, const float* __restrict__ b_univ,
    const float* __restrict__ W_att, const float* __restrict__ b_att,
    const float* __restrict__ W_fin, const float* __restrict__ b_fin,
    const int* __restrict__ pred_ids, const int* __restrict__ var_ids,
    const int* __restrict__ op_ids,
    const float* __restrict__ ws, float* __restrict__ out)
{
    __shared__ float ldsf[LDS_FLOATS];          // 79872 B
    __half* ldsh = (__half*)ldsf;
    const int tid = threadIdx.x;
    const int wave = tid >> 6, lane = tid & 63;
    const int pi = wave & 1, pairid = wave >> 1;
    const int nl = pairid*64 + lane;            // node-local 0..255
    const int blockbase = blockIdx.x * 256;
    const int j = blockbase + nl;

    // ---- stage fp16 T+ve (70000 B) + fp32 logits ----
    {
        const uint4* src = (const uint4*)ws;    // halves [0..35000) = 4375 uint4
        uint4* dst = (uint4*)ldsh;
        for (int i = tid; i < 4375; i += 512) dst[i] = src[i];
        if (tid < 300) ldsf[O_LG_LDS + tid] = ws[F_LG + tid];
    }
    __syncthreads();                            // B1

    const float* lgl = ldsf + O_LG_LDS;
    const float batt = b_att[0];
    const __half2* peg = (const __half2*)((const __half*)ws + H_PE);

    int vA[5], vB[5];
    const int pA = pred_ids[2*j], pB = pred_ids[2*j+1];
#pragma unroll
    for (int s = 0; s < 5; ++s) { vA[s] = var_ids[(2*j)*5 + s]; vB[s] = var_ids[(2*j+1)*5 + s]; }
    const int op = op_ids[j];

    float ekA[5], ekB[5];
    const float e0A = __expf(lgl[pA]);
    const float e0B = __expf(lgl[pB]);
    float denA = e0A, denB = e0B;
#pragma unroll
    for (int s = 0; s < 5; ++s) {
        ekA[s] = __expf(lgl[VOCABSZ + vA[s]]); denA += ekA[s];
        ekB[s] = __expf(lgl[VOCABSZ + vB[s]]); denB += ekB[s];
    }
    const float invA = 1.0f / denA, invB = 1.0f / denB;
    const float w1 = __expf(lgl[2*VOCABSZ + op]);

    if (pi == 0)
        work<0>(nl, lane, wave, pairid, blockbase, pA, pB, vA, vB, op,
                e0A, e0B, ekA, ekB, invA, invB, w1, batt, ldsf, ldsh, peg,
                oe, W_bin, W_un, b_un, W_univ, b_univ, W_att, W_fin, b_fin, ws, out);
    else
        work<1>(nl, lane, wave, pairid, blockbase, pA, pB, vA, vB, op,
                e0A, e0B, ekA, ekB, invA, invB, w1, batt, ldsf, ldsh, peg,
                oe, W_bin, W_un, b_un, W_univ, b_univ, W_att, W_fin, b_fin, ws, out);
}

// ---------------------------------------------------------------------------
extern "C" void kernel_launch(void* const* d_in, const int* in_sizes, int n_in,
                              void* d_out, int out_size, void* d_ws, size_t ws_size,
                              hipStream_t stream) {
    const float* pe     = (const float*)d_in[0];
    const float* ve     = (const float*)d_in[1];
    const float* oe     = (const float*)d_in[2];
    const float* W_pred = (const float*)d_in[3];
    const float* b_pred = (const float*)d_in[4];
    const float* W_bin  = (const float*)d_in[5];
    const float* b_bin  = (const float*)d_in[6];
    const float* W_un   = (const float*)d_in[7];
    const float* b_un   = (const float*)d_in[8];
    const float* W_univ = (const float*)d_in[9];
    const float* b_univ = (const float*)d_in[10];
    const float* W_att  = (const float*)d_in[11];
    const float* b_att  = (const float*)d_in[12];
    const float* W_fin  = (const float*)d_in[13];
    const float* b_fin  = (const float*)d_in[14];
    const int* pred_ids = (const int*)d_in[15];
    const int* var_ids  = (const int*)d_in[16];
    const int* op_ids   = (const int*)d_in[17];
    float* out = (float*)d_out;
    float* ws  = (float*)d_ws;

    precompute_kernel<<<905, 64, 0, stream>>>(pe, ve, oe, W_pred, b_pred,
                                              W_bin, b_bin, W_att, b_att, ws);
    fused_kernel<<<MBIN/256, 512, 0, stream>>>(oe, W_bin, W_un, b_un,
                                               W_univ, b_univ, W_att, b_att,
                                               W_fin, b_fin, pred_ids, var_ids,
                                               op_ids, ws, out);
}

// Round 11
// 360.763 us; speedup vs baseline: 7.0470x; 7.0470x over previous
//
#include <hip/hip_runtime.h>
#include <hip/hip_fp16.h>

#define LDIM 50
#define MBIN 262144
#define ODIM 155
#define VOCABSZ 100

typedef _Float16 f16x4 __attribute__((ext_vector_type(4)));
typedef float    f32x4 __attribute__((ext_vector_type(4)));

// ---- workspace half-offsets (from (__half*)ws) ----
#define H_T    0       // [600][50] fp16 T tables (s=0 pe-slot w/ b_pred; s=1..5 ve-slots)
#define H_PE   30000   // [100][50] pe fp16
#define H_VE   35000   // [100][50] ve fp16
#define H_TO   40000   // [100][50] half2 pairs {Tb, oe}  (10000 halves)
#define H_WC   50000   // WtCat  [64][116] fp16 : B^T of GEMM1 (rows n, cols k; zero-padded)
#define H_WU   57424   // W_unT  [64][68]
#define H_WV   61776   // W_univT[64][68]
#define H_WF   66128   // W_finT [160][68]
#define F_LG   38504   // float-offset: 300 attention logits fp32

// ---- LDS byte offsets (static 161456 B) ----
#define LB_WC   118784
#define LB_WU   133632
#define LB_WV   142336
#define LB_WF   118784   // overlays Wc+Wu after GEMM2 (21760 B)
#define LB_SW   140544   // 8 waves x 16x17 f32 transpose buffers (overlays Wu/Wv tails, GEMM4 only)
#define LB_OP   151040
#define LB_W0   153088
#define LB_W2   155136
#define LB_W1   157184
#define LB_BU   159232
#define LB_BV   159432
#define LB_BF   159632
#define LB_LG   160256
#define LDS_BYTES 161456

// ---------------------------------------------------------------------------
// Precompute: fp16 gather tables + fp32 logits + fp16 TRANSPOSED weight tables
// ---------------------------------------------------------------------------
__global__ __launch_bounds__(64) void precompute_kernel(
    const float* __restrict__ pe, const float* __restrict__ ve, const float* __restrict__ oe,
    const float* __restrict__ W_pred, const float* __restrict__ b_pred,
    const float* __restrict__ W_bin, const float* __restrict__ b_bin,
    const float* __restrict__ W_un, const float* __restrict__ W_univ,
    const float* __restrict__ W_fin,
    const float* __restrict__ W_att, const float* __restrict__ b_att,
    float* __restrict__ ws)
{
    __half* wsh = (__half*)ws;
    const int bid = blockIdx.x;
    const int t = threadIdx.x;
    if (bid < 600) {                    // T tables fp16
        const int s = bid / VOCABSZ, v = bid % VOCABSZ;
        if (t < LDIM) {
            const float* E = (s == 0) ? pe : ve;
            float acc = (s == 0) ? b_pred[t] : 0.0f;
            for (int e = 0; e < LDIM; ++e)
                acc += E[v*LDIM + e] * W_pred[(s*LDIM + e)*LDIM + t];
            wsh[H_T + (s*VOCABSZ + v)*LDIM + t] = __float2half_rn(acc);
        }
    } else if (bid < 700) {             // TO = {Tb, oe} half2 pairs
        const int v = bid - 600;
        if (t < LDIM) {
            float acc = b_bin[t];
            for (int e = 0; e < LDIM; ++e)
                acc += oe[v*LDIM + e] * W_bin[(LDIM + e)*LDIM + t];
            wsh[H_TO + (v*LDIM + t)*2]     = __float2half_rn(acc);
            wsh[H_TO + (v*LDIM + t)*2 + 1] = __float2half_rn(oe[v*LDIM + t]);
        }
    } else if (bid < 800) {             // pe fp16
        const int v = bid - 700;
        if (t < LDIM) wsh[H_PE + v*LDIM + t] = __float2half_rn(pe[v*LDIM + t]);
    } else if (bid < 900) {             // ve fp16
        const int v = bid - 800;
        if (t < LDIM) wsh[H_VE + v*LDIM + t] = __float2half_rn(ve[v*LDIM + t]);
    } else if (bid < 905) {             // logits fp32
        const int g = (bid - 900)*64 + t;
        if (g < 300) {
            const int which = g / VOCABSZ, v = g % VOCABSZ;
            const float* E = (which == 0) ? pe : ((which == 1) ? ve : oe);
            float acc = b_att[0];
            for (int e = 0; e < LDIM; ++e)
                acc += E[v*LDIM + e] * W_att[e];
            ws[F_LG + g] = acc;
        }
    } else if (bid == 905) {            // WtCat [64][116]: B[k][n] of GEMM1, transposed
        const int n = t;                 // 0..63
        for (int k = 0; k < 116; ++k) {
            float val = 0.0f;
            if (n < LDIM) {
                if (k < 50)       val = W_bin[k*LDIM + n];            // hA rows 0..49
                else if (k < 100) val = W_bin[(100 + k - 50)*LDIM + n]; // hB rows 100..149
            }
            wsh[H_WC + n*116 + k] = __float2half_rn(val);
        }
    } else if (bid == 906) {            // W_unT [64][68]
        const int n = t;
        for (int k = 0; k < 68; ++k) {
            float val = (n < LDIM && k < LDIM) ? W_un[k*LDIM + n] : 0.0f;
            wsh[H_WU + n*68 + k] = __float2half_rn(val);
        }
    } else if (bid == 907) {            // W_univT [64][68]
        const int n = t;
        for (int k = 0; k < 68; ++k) {
            float val = (n < LDIM && k < LDIM) ? W_univ[k*LDIM + n] : 0.0f;
            wsh[H_WV + n*68 + k] = __float2half_rn(val);
        }
    } else {                            // 908..910: W_finT [160][68]
        const int n = (bid - 908)*64 + t;
        if (n < 160) {
            for (int k = 0; k < 68; ++k) {
                float val = (n < ODIM && k < LDIM) ? W_fin[k*ODIM + n] : 0.0f;
                wsh[H_WF + n*68 + k] = __float2half_rn(val);
            }
        }
    }
}

// ---------------------------------------------------------------------------
// h pair (dims 2i,2i+1) of pred node from fp16 LDS tables (round-8 proven math)
// ---------------------------------------------------------------------------
__device__ __forceinline__ float2 nodeh(
    int i, int p, const int* __restrict__ v,
    float e0, const float* __restrict__ ek, float inv, const char* __restrict__ ldsraw)
{
    const __half2* T2  = (const __half2*)ldsraw;            // halves [0..30000)
    const __half2* pe2 = (const __half2*)(ldsraw + 60000);  // halves 30000..
    const __half2* ve2 = (const __half2*)(ldsraw + 70000);  // halves 35000..
    float2 lin = __half22float2(T2[p*25 + i]);
    float2 pv  = __half22float2(pe2[p*25 + i]);
    float nx = e0*pv.x, ny = e0*pv.y;
#pragma unroll
    for (int s = 0; s < 5; ++s) {
        float2 a = __half22float2(T2[((s+1)*VOCABSZ + v[s])*25 + i]);
        float2 b = __half22float2(ve2[v[s]*25 + i]);
        lin.x += a.x; lin.y += a.y;
        nx += ek[s]*b.x; ny += ek[s]*b.y;
    }
    return make_float2(fmaxf(lin.x, 0.0f) + nx*inv,
                       fmaxf(lin.y, 0.0f) + ny*inv);
}

// ---------------------------------------------------------------------------
// Fused kernel: 512 thr, 512 bin-nodes/block. Wave w owns nodes w*64..w*64+63
// end-to-end (self-contained rows -> minimal barriers).
// P1: VALU gather-build (fp16 LDS tables) -> hA/hB packed regs + softmax w's.
// Tables then DIE; H[512][116] fp16 overlays them. GEMM1..4 on MFMA
// (v_mfma_f32_16x16x16_f16, fp32 accum), weights pre-transposed fp16 in LDS.
// A-frag: lane reads A[row=l&15][k=(l>>4)*4+i]; B-frag: Wt[n=l&15][same k];
// D: row=(l>>4)*4+r, col=l&15  (verified CDNA mappings).
// ---------------------------------------------------------------------------
__global__ __launch_bounds__(512)
void fused_kernel(
    const float* __restrict__ W_att, const float* __restrict__ b_att,
    const float* __restrict__ b_un, const float* __restrict__ b_univ,
    const float* __restrict__ b_fin,
    const int* __restrict__ pred_ids, const int* __restrict__ var_ids,
    const int* __restrict__ op_ids,
    const float* __restrict__ ws, float* __restrict__ out)
{
    __shared__ __align__(16) char ldsraw[LDS_BYTES];
    const __half* wsh = (const __half*)ws;
    const int tid = threadIdx.x;
    const int w = tid >> 6, l = tid & 63;
    const int lr = l & 15, q = l >> 4;
    const int jbase = blockIdx.x * 512;

    int*   opl = (int*)(ldsraw + LB_OP);
    float* w0l = (float*)(ldsraw + LB_W0);
    float* w2l = (float*)(ldsraw + LB_W2);
    float* w1l = (float*)(ldsraw + LB_W1);
    float* bul = (float*)(ldsraw + LB_BU);
    float* bvl = (float*)(ldsraw + LB_BV);
    float* bfl = (float*)(ldsraw + LB_BF);
    float* lgl = (float*)(ldsraw + LB_LG);

    // ---- P0: stage tables (80000B) + Wc/Wu/Wv + biases + lg ----
    {
        const uint4* s = (const uint4*)wsh;                 // halves [0..40000)
        uint4* d = (uint4*)ldsraw;
        for (int i = tid; i < 5000; i += 512) d[i] = s[i];
        const uint2* sc = (const uint2*)(wsh + H_WC);
        uint2* dc = (uint2*)(ldsraw + LB_WC);
        for (int i = tid; i < 1856; i += 512) dc[i] = sc[i];
        const uint2* su = (const uint2*)(wsh + H_WU);
        uint2* du = (uint2*)(ldsraw + LB_WU);
        for (int i = tid; i < 1088; i += 512) du[i] = su[i];
        const uint2* sv = (const uint2*)(wsh + H_WV);
        uint2* dv = (uint2*)(ldsraw + LB_WV);
        for (int i = tid; i < 1088; i += 512) dv[i] = sv[i];
        if (tid < 300) lgl[tid] = ws[F_LG + tid];
        if (tid < LDIM) { bul[tid] = b_un[tid]; bvl[tid] = b_univ[tid]; }
        if (tid < ODIM) bfl[tid] = b_fin[tid];
    }
    __syncthreads();                                        // B0

    // ---- P1: gather-build hA,hB (packed fp16 regs) + softmax scalars ----
    const int j = jbase + tid;
    int vA[5], vB[5];
    const int pA = pred_ids[2*j], pB = pred_ids[2*j+1];
#pragma unroll
    for (int s = 0; s < 5; ++s) { vA[s] = var_ids[(2*j)*5 + s]; vB[s] = var_ids[(2*j+1)*5 + s]; }
    const int op = op_ids[j];

    float ekA[5], ekB[5];
    const float e0A = __expf(lgl[pA]);
    const float e0B = __expf(lgl[pB]);
    float denA = e0A, denB = e0B;
#pragma unroll
    for (int s = 0; s < 5; ++s) {
        ekA[s] = __expf(lgl[VOCABSZ + vA[s]]); denA += ekA[s];
        ekB[s] = __expf(lgl[VOCABSZ + vB[s]]); denB += ekB[s];
    }
    const float invA = 1.0f / denA, invB = 1.0f / denB;
    const float batt = b_att[0];

    __half2 hA2[25], hB2[25];
    float lA = batt, lB = batt;
    const float2* Wa2 = (const float2*)W_att;
#pragma unroll
    for (int i = 0; i < 25; ++i) {
        float2 a = nodeh(i, pA, vA, e0A, ekA, invA, ldsraw);
        float2 b = nodeh(i, pB, vB, e0B, ekB, invB, ldsraw);
        hA2[i] = __floats2half2_rn(a.x, a.y);
        hB2[i] = __floats2half2_rn(b.x, b.y);
        const float2 wa = Wa2[i];
        lA += a.x*wa.x + a.y*wa.y;
        lB += b.x*wa.x + b.y*wa.y;
    }
    const float w0 = __expf(lA), w2 = __expf(lB);
    const float w1 = __expf(lgl[2*VOCABSZ + op]);
    const float inv2 = 1.0f / (w0 + w1 + w2);

    __syncthreads();                                        // B1: table reads done -> overlay

    // ---- write H row [tid][116] (hA|hB|zeros) + scalars ----
    {
        __half2* Hrow = (__half2*)ldsraw + tid*58;          // 116 halves
#pragma unroll
        for (int i = 0; i < 25; ++i) Hrow[i] = hA2[i];
#pragma unroll
        for (int i = 0; i < 25; ++i) Hrow[25+i] = hB2[i];
        const __half2 z = __floats2half2_rn(0.0f, 0.0f);
#pragma unroll
        for (int i = 50; i < 58; ++i) Hrow[i] = z;
        opl[tid] = op;
        w0l[tid] = w0*inv2; w2l[tid] = w2*inv2; w1l[tid] = w1*inv2;
    }
    // (no barrier: each wave reads only its own 64 rows/scalars below)

    const _Float16* Hp  = (const _Float16*)ldsraw;
    __half*         Hw  = (__half*)ldsraw;
    f32x4 C[4][4];

    // ---- P2: GEMM1  lin2[512x64] = H[512x116(100)] @ Wcat ----
    {
        const _Float16* Wcp = (const _Float16*)(ldsraw + LB_WC);
#pragma unroll
        for (int mt = 0; mt < 4; ++mt)
#pragma unroll
            for (int nt = 0; nt < 4; ++nt)
                C[mt][nt] = (f32x4){0.f, 0.f, 0.f, 0.f};
#pragma unroll
        for (int kk = 0; kk < 7; ++kk) {
            f16x4 bf[4];
#pragma unroll
            for (int nt = 0; nt < 4; ++nt)
                bf[nt] = *(const f16x4*)(Wcp + (nt*16 + lr)*116 + kk*16 + q*4);
#pragma unroll
            for (int mt = 0; mt < 4; ++mt) {
                f16x4 a = *(const f16x4*)(Hp + (w*64 + mt*16 + lr)*116 + kk*16 + q*4);
#pragma unroll
                for (int nt = 0; nt < 4; ++nt)
                    C[mt][nt] = __builtin_amdgcn_mfma_f32_16x16x16f16(a, bf[nt], C[mt][nt], 0, 0, 0);
            }
        }
        // epilogue: h_bin = relu(lin2 + Tb[op]) + w0i*hA + w2i*hB + w1i*oe[op]
        const __half2* TOg = (const __half2*)(wsh + H_TO);
#pragma unroll
        for (int mt = 0; mt < 4; ++mt)
#pragma unroll
            for (int nt = 0; nt < 4; ++nt) {
                const int d = nt*16 + lr;
#pragma unroll
                for (int r = 0; r < 4; ++r) {
                    const int node = w*64 + mt*16 + q*4 + r;
                    float v = 0.0f;
                    if (d < LDIM) {
                        const int opn = opl[node];
                        const float2 to = __half22float2(TOg[opn*LDIM + d]);   // {Tb, oe}
                        const float hA = __half2float(Hp[node*116 + d]);
                        const float hB = __half2float(Hp[node*116 + 50 + d]);
                        v = fmaxf(C[mt][nt][r] + to.x, 0.0f)
                          + w0l[node]*hA + w2l[node]*hB + w1l[node]*to.y;
                    }
                    C[mt][nt][r] = v;
                }
            }
    }
    __syncthreads();        // B2: all epilogue READS of stride-116 H done before stride-68 writes
#pragma unroll
    for (int mt = 0; mt < 4; ++mt)
#pragma unroll
        for (int nt = 0; nt < 4; ++nt) {
            const int d = nt*16 + lr;
#pragma unroll
            for (int r = 0; r < 4; ++r)
                Hw[(w*64 + mt*16 + q*4 + r)*68 + d] = __float2half(C[mt][nt][r]);
        }
    // (own-wave rows only -> no barrier; within-wave LDS ordering suffices)

    // ---- P3: GEMM2  h_un = relu(h_bin @ W_un + b_un) ----
    {
        const _Float16* Wup = (const _Float16*)(ldsraw + LB_WU);
#pragma unroll
        for (int mt = 0; mt < 4; ++mt)
#pragma unroll
            for (int nt = 0; nt < 4; ++nt)
                C[mt][nt] = (f32x4){0.f, 0.f, 0.f, 0.f};
#pragma unroll
        for (int kk = 0; kk < 4; ++kk) {
            f16x4 bf[4];
#pragma unroll
            for (int nt = 0; nt < 4; ++nt)
                bf[nt] = *(const f16x4*)(Wup + (nt*16 + lr)*68 + kk*16 + q*4);
#pragma unroll
            for (int mt = 0; mt < 4; ++mt) {
                f16x4 a = *(const f16x4*)(Hp + (w*64 + mt*16 + lr)*68 + kk*16 + q*4);
#pragma unroll
                for (int nt = 0; nt < 4; ++nt)
                    C[mt][nt] = __builtin_amdgcn_mfma_f32_16x16x16f16(a, bf[nt], C[mt][nt], 0, 0, 0);
            }
        }
    }
    __syncthreads();        // B3: all GEMM2 Kloops done (Wc+Wu dead -> Wf overlay safe)
    {
        // write h_un (own rows) + stage W_finT cooperatively
#pragma unroll
        for (int mt = 0; mt < 4; ++mt)
#pragma unroll
            for (int nt = 0; nt < 4; ++nt) {
                const int d = nt*16 + lr;
#pragma unroll
                for (int r = 0; r < 4; ++r) {
                    const float v = (d < LDIM) ? fmaxf(C[mt][nt][r] + bul[d], 0.0f) : 0.0f;
                    Hw[(w*64 + mt*16 + q*4 + r)*68 + d] = __float2half(v);
                }
            }
        const uint2* sf = (const uint2*)(wsh + H_WF);
        uint2* df = (uint2*)(ldsraw + LB_WF);
        for (int i = tid; i < 2720; i += 512) df[i] = sf[i];
    }

    // ---- P4: GEMM3  h_q = relu(h_un @ W_univ + b_univ) ----
    {
        const _Float16* Wvp = (const _Float16*)(ldsraw + LB_WV);
#pragma unroll
        for (int mt = 0; mt < 4; ++mt)
#pragma unroll
            for (int nt = 0; nt < 4; ++nt)
                C[mt][nt] = (f32x4){0.f, 0.f, 0.f, 0.f};
#pragma unroll
        for (int kk = 0; kk < 4; ++kk) {
            f16x4 bf[4];
#pragma unroll
            for (int nt = 0; nt < 4; ++nt)
                bf[nt] = *(const f16x4*)(Wvp + (nt*16 + lr)*68 + kk*16 + q*4);
#pragma unroll
            for (int mt = 0; mt < 4; ++mt) {
                f16x4 a = *(const f16x4*)(Hp + (w*64 + mt*16 + lr)*68 + kk*16 + q*4);
#pragma unroll
                for (int nt = 0; nt < 4; ++nt)
                    C[mt][nt] = __builtin_amdgcn_mfma_f32_16x16x16f16(a, bf[nt], C[mt][nt], 0, 0, 0);
            }
        }
#pragma unroll
        for (int mt = 0; mt < 4; ++mt)
#pragma unroll
            for (int nt = 0; nt < 4; ++nt) {
                const int d = nt*16 + lr;
#pragma unroll
                for (int r = 0; r < 4; ++r) {
                    const float v = (d < LDIM) ? fmaxf(C[mt][nt][r] + bvl[d], 0.0f) : 0.0f;
                    Hw[(w*64 + mt*16 + q*4 + r)*68 + d] = __float2half(v);
                }
            }
    }
    __syncthreads();        // B5: all GEMM3 Kloops done (Wv dead -> sw overlay safe; Wf staged)

    // ---- P5: GEMM4  out = h_q @ W_fin + b_fin  (per-tile, LDS-transposed stores) ----
    {
        const _Float16* Wfp = (const _Float16*)(ldsraw + LB_WF);
        float* sww = (float*)(ldsraw + LB_SW) + w*272;      // 16x17 per wave
        for (int nt = 0; nt < 10; ++nt) {
            f16x4 bf[4];
#pragma unroll
            for (int kk = 0; kk < 4; ++kk)
                bf[kk] = *(const f16x4*)(Wfp + (nt*16 + lr)*68 + kk*16 + q*4);
            const int o = nt*16 + lr;
#pragma unroll
            for (int mt = 0; mt < 4; ++mt) {
                f32x4 c = (f32x4){0.f, 0.f, 0.f, 0.f};
#pragma unroll
                for (int kk = 0; kk < 4; ++kk) {
                    f16x4 a = *(const f16x4*)(Hp + (w*64 + mt*16 + lr)*68 + kk*16 + q*4);
                    c = __builtin_amdgcn_mfma_f32_16x16x16f16(a, bf[kk], c, 0, 0, 0);
                }
#pragma unroll
                for (int r = 0; r < 4; ++r)
                    sww[(q*4 + r)*17 + lr] = c[r] + ((o < ODIM) ? bfl[o] : 0.0f);
                // wave-synchronous transpose read-out: 64B row bursts
                float* gb = out + (size_t)(jbase + w*64 + mt*16) * ODIM + nt*16;
#pragma unroll
                for (int it = 0; it < 4; ++it) {
                    const int row = it*4 + q;
                    if (nt*16 + lr < ODIM)
                        gb[row*ODIM + lr] = sww[row*17 + lr];
                }
            }
        }
    }
}

// ---------------------------------------------------------------------------
extern "C" void kernel_launch(void* const* d_in, const int* in_sizes, int n_in,
                              void* d_out, int out_size, void* d_ws, size_t ws_size,
                              hipStream_t stream) {
    const float* pe     = (const float*)d_in[0];
    const float* ve     = (const float*)d_in[1];
    const float* oe     = (const float*)d_in[2];
    const float* W_pred = (const float*)d_in[3];
    const float* b_pred = (const float*)d_in[4];
    const float* W_bin  = (const float*)d_in[5];
    const float* b_bin  = (const float*)d_in[6];
    const float* W_un   = (const float*)d_in[7];
    const float* b_un   = (const float*)d_in[8];
    const float* W_univ = (const float*)d_in[9];
    const float* b_univ = (const float*)d_in[10];
    const float* W_att  = (const float*)d_in[11];
    const float* b_att  = (const float*)d_in[12];
    const float* W_fin  = (const float*)d_in[13];
    const float* b_fin  = (const float*)d_in[14];
    const int* pred_ids = (const int*)d_in[15];
    const int* var_ids  = (const int*)d_in[16];
    const int* op_ids   = (const int*)d_in[17];
    float* out = (float*)d_out;
    float* ws  = (float*)d_ws;

    precompute_kernel<<<911, 64, 0, stream>>>(pe, ve, oe, W_pred, b_pred,
                                              W_bin, b_bin, W_un, W_univ, W_fin,
                                              W_att, b_att, ws);
    fused_kernel<<<MBIN/512, 512, 0, stream>>>(W_att, b_att, b_un, b_univ, b_fin,
                                               pred_ids, var_ids, op_ids, ws, out);
}

// Round 12
// 335.068 us; speedup vs baseline: 7.5874x; 1.0767x over previous
//
#include <hip/hip_runtime.h>
#include <hip/hip_fp16.h>

#define LDIM 50
#define MBIN 262144
#define ODIM 155
#define VOCABSZ 100

typedef _Float16 f16x4 __attribute__((ext_vector_type(4)));
typedef float    f32x4 __attribute__((ext_vector_type(4)));

// ---- workspace half-offsets (from (__half*)ws) ----
// padded gather tables, row stride 56 halves (112 B, 16B-aligned):
//   rows 0..599   : T[s][v]  (s=0 pe-slot w/ b_pred; s=1..5 ve-slots)
//   rows 600..699 : pe
//   rows 700..799 : ve
#define H_TBL  0       // 800*56 = 44800 halves
#define H_TO   44800   // [100][50] half2 pairs {Tb, oe} -> 10000 halves
#define H_WC   54800   // WtCat  [64][116] : B^T of GEMM1 (zero-padded)
#define H_WU   62224   // W_unT  [64][68]
#define H_WV   66576   // W_univT[64][68]
#define H_WF   70928   // W_finT [160][68]  (ends 81808)
#define F_LG   40960   // float-offset: 300 attention logits fp32 (halves 81920..)

// ---- LDS byte offsets (static 161680 B) ----
// [0..89600) padded tables (build phase); H[512][116] fp16 overlays [0..118784)
#define LB_WC   118784   // 14848 B
#define LB_WU   133632   // 8704 B
#define LB_WV   142336   // 8704 B
#define LB_WF   118784   // overlays Wc+Wu after GEMM2 (21760 B)
#define LB_SW   140544   // 8 waves x 16x17 f32 (P5 only; overlays Wu/Wv tails)
#define LB_OP   151040
#define LB_W0   153088
#define LB_W2   155136
#define LB_W1   157184
#define LB_BU   159232
#define LB_BV   159432
#define LB_BF   159632
#define LB_LG   160256
#define LB_WATT 161456   // 56 fl padded W_att
#define LDS_BYTES 161680

// ---------------------------------------------------------------------------
// Precompute: 256-thr blocks, unrolled coalesced loops (round-11 lesson: the
// 911x64 single-wave version was comparable in cost to the MAIN kernel).
// ---------------------------------------------------------------------------
__global__ __launch_bounds__(256) void precompute_kernel(
    const float* __restrict__ pe, const float* __restrict__ ve, const float* __restrict__ oe,
    const float* __restrict__ W_pred, const float* __restrict__ b_pred,
    const float* __restrict__ W_bin, const float* __restrict__ b_bin,
    const float* __restrict__ W_un, const float* __restrict__ W_univ,
    const float* __restrict__ W_fin,
    const float* __restrict__ W_att, const float* __restrict__ b_att,
    float* __restrict__ ws)
{
    __half* wsh = (__half*)ws;
    const int bid = blockIdx.x, tid = threadIdx.x;
    if (bid < 150) {                        // T tables: 4 rows/block, padded to 56
        const int row = bid*4 + (tid >> 6);          // 0..599
        const int t = tid & 63;
        const int s = row / VOCABSZ, v = row % VOCABSZ;
        if (t < 56) {
            float acc = 0.0f;
            if (t < 50) {
                acc = (s == 0) ? b_pred[t] : 0.0f;
                const float* E = (s == 0) ? pe : ve;
#pragma unroll
                for (int e = 0; e < 50; ++e)
                    acc += E[v*50 + e] * W_pred[(s*50 + e)*50 + t];
            }
            wsh[H_TBL + row*56 + t] = __float2half_rn(acc);
        }
    } else if (bid < 152) {                 // pe/ve padded fp16 copies
        const int which = bid - 150;        // 0: pe, 1: ve
        const float* E = which ? ve : pe;
        const int base = H_TBL + (600 + which*100) * 56;
        for (int idx = tid; idx < 5600; idx += 256) {
            const int r = idx / 56, c = idx % 56;
            wsh[base + idx] = __float2half_rn((c < 50) ? E[r*50 + c] : 0.0f);
        }
    } else if (bid < 177) {                 // TO = {Tb, oe} pairs: 4 v/block
        const int v = (bid - 152)*4 + (tid >> 6);
        const int t = tid & 63;
        if (t < 50) {
            float acc = b_bin[t];
#pragma unroll
            for (int e = 0; e < 50; ++e)
                acc += oe[v*50 + e] * W_bin[(50 + e)*50 + t];
            wsh[H_TO + (v*50 + t)*2]     = __float2half_rn(acc);
            wsh[H_TO + (v*50 + t)*2 + 1] = __float2half_rn(oe[v*50 + t]);
        }
    } else if (bid == 177) {                // WC [64][116]
        const int n = tid & 63, kc = tid >> 6;
        for (int k = kc*29; k < kc*29 + 29; ++k) {
            float val = 0.0f;
            if (n < 50) {
                if (k < 50)       val = W_bin[k*50 + n];
                else if (k < 100) val = W_bin[(100 + k - 50)*50 + n];
            }
            wsh[H_WC + n*116 + k] = __float2half_rn(val);
        }
    } else if (bid == 178) {                // WU + WV [64][68]
        const int n = tid & 63;
        const int half = tid >> 7;          // 0: WU, 1: WV
        const int kc = (tid >> 6) & 1;
        const float* W = half ? W_univ : W_un;
        const int base = half ? H_WV : H_WU;
        for (int k = kc*34; k < kc*34 + 34; ++k) {
            float val = (n < 50 && k < 50) ? W[k*50 + n] : 0.0f;
            wsh[base + n*68 + k] = __float2half_rn(val);
        }
    } else if (bid == 179) {                // WF [160][68] (n-major idx -> coalesced reads)
        for (int idx = tid; idx < 10880; idx += 256) {
            const int n = idx % 160, k = idx / 160;
            float val = (n < ODIM && k < 50) ? W_fin[k*ODIM + n] : 0.0f;
            wsh[H_WF + n*68 + k] = __float2half_rn(val);
        }
    } else {                                // bid == 180: logits fp32
        for (int g = tid; g < 300; g += 256) {
            const int which = g / VOCABSZ, v = g % VOCABSZ;
            const float* E = (which == 0) ? pe : ((which == 1) ? ve : oe);
            float acc = b_att[0];
#pragma unroll
            for (int e = 0; e < 50; ++e)
                acc += E[v*50 + e] * W_att[e];
            ws[F_LG + g] = acc;
        }
    }
}

// ---------------------------------------------------------------------------
// Build one predicate node from padded fp16 LDS tables with uint4 (16B) loads:
// 12 ds_read_b128 per 8-dim group (vs 48 ds_read_b32 before). Returns exp(logit).
// Pad dims 50..55 are exact zeros (tables zero-padded) -> h=0, logit term 0.
// ---------------------------------------------------------------------------
__device__ __forceinline__ float build_node(
    int p, const int* __restrict__ v, float e0, const float* __restrict__ ek,
    float inv, float batt, const char* __restrict__ ldsraw, __half2* __restrict__ h2)
{
    const uint4* Tq = (const uint4*)ldsraw;       // row stride 7 uint4 (56 halves)
    const float* wattl = (const float*)(ldsraw + LB_WATT);
    float l = batt;
#pragma unroll
    for (int g = 0; g < 7; ++g) {
        uint4 ul = Tq[p*7 + g];                   // T pred row (b_pred folded)
        uint4 up = Tq[(600 + p)*7 + g];           // pe row
        float2 lin[4], num[4];
#pragma unroll
        for (int k = 0; k < 4; ++k) {
            lin[k] = __half22float2(((const __half2*)&ul)[k]);
            float2 pp = __half22float2(((const __half2*)&up)[k]);
            num[k] = make_float2(e0*pp.x, e0*pp.y);
        }
#pragma unroll
        for (int s = 0; s < 5; ++s) {
            uint4 ua = Tq[((s+1)*VOCABSZ + v[s])*7 + g];   // T arg-slot row
            uint4 uv = Tq[(700 + v[s])*7 + g];             // ve row
#pragma unroll
            for (int k = 0; k < 4; ++k) {
                float2 a = __half22float2(((const __half2*)&ua)[k]);
                float2 b = __half22float2(((const __half2*)&uv)[k]);
                lin[k].x += a.x; lin[k].y += a.y;
                num[k].x += ek[s]*b.x; num[k].y += ek[s]*b.y;
            }
        }
#pragma unroll
        for (int k = 0; k < 4; ++k) {
            const float hx = fmaxf(lin[k].x, 0.0f) + num[k].x*inv;
            const float hy = fmaxf(lin[k].y, 0.0f) + num[k].y*inv;
            l += hx*wattl[g*8 + 2*k] + hy*wattl[g*8 + 2*k + 1];
            h2[g*4 + k] = __floats2half2_rn(hx, hy);
        }
    }
    return __expf(l);
}

// ---------------------------------------------------------------------------
// Fused kernel (round-11 structure, proven): 512 thr, wave w owns 64 nodes.
// P1 gather-build (now uint4 loads) -> H[512][116] fp16 overlays tables ->
// GEMM1..4 on v_mfma_f32_16x16x16_f16 with pre-transposed fp16 weights.
// ---------------------------------------------------------------------------
__global__ __launch_bounds__(512)
void fused_kernel(
    const float* __restrict__ W_att, const float* __restrict__ b_att,
    const float* __restrict__ b_un, const float* __restrict__ b_univ,
    const float* __restrict__ b_fin,
    const int* __restrict__ pred_ids, const int* __restrict__ var_ids,
    const int* __restrict__ op_ids,
    const float* __restrict__ ws, float* __restrict__ out)
{
    __shared__ __align__(16) char ldsraw[LDS_BYTES];
    const __half* wsh = (const __half*)ws;
    const int tid = threadIdx.x;
    const int w = tid >> 6, l = tid & 63;
    const int lr = l & 15, q = l >> 4;
    const int jbase = blockIdx.x * 512;

    int*   opl = (int*)(ldsraw + LB_OP);
    float* w0l = (float*)(ldsraw + LB_W0);
    float* w2l = (float*)(ldsraw + LB_W2);
    float* w1l = (float*)(ldsraw + LB_W1);
    float* bul = (float*)(ldsraw + LB_BU);
    float* bvl = (float*)(ldsraw + LB_BV);
    float* bfl = (float*)(ldsraw + LB_BF);
    float* lgl = (float*)(ldsraw + LB_LG);
    float* wattl = (float*)(ldsraw + LB_WATT);

    // ---- P0: stage padded tables (89600B) + Wc/Wu/Wv + biases + lg + watt ----
    {
        const uint4* s = (const uint4*)wsh;                 // 5600 uint4
        uint4* d = (uint4*)ldsraw;
        for (int i = tid; i < 5600; i += 512) d[i] = s[i];
        const uint2* sc = (const uint2*)(wsh + H_WC);
        uint2* dc = (uint2*)(ldsraw + LB_WC);
        for (int i = tid; i < 1856; i += 512) dc[i] = sc[i];
        const uint2* su = (const uint2*)(wsh + H_WU);
        uint2* du = (uint2*)(ldsraw + LB_WU);
        for (int i = tid; i < 1088; i += 512) du[i] = su[i];
        const uint2* sv = (const uint2*)(wsh + H_WV);
        uint2* dv = (uint2*)(ldsraw + LB_WV);
        for (int i = tid; i < 1088; i += 512) dv[i] = sv[i];
        if (tid < 300) lgl[tid] = ws[F_LG + tid];
        if (tid < LDIM) { bul[tid] = b_un[tid]; bvl[tid] = b_univ[tid]; }
        if (tid < ODIM) bfl[tid] = b_fin[tid];
        if (tid >= 256 && tid < 312) wattl[tid-256] = (tid-256 < 50) ? W_att[tid-256] : 0.0f;
    }
    __syncthreads();                                        // B0

    // ---- P1: gather-build hA,hB (uint4 loads) + softmax scalars ----
    const int j = jbase + tid;
    int vA[5], vB[5];
    const int pA = pred_ids[2*j], pB = pred_ids[2*j+1];
#pragma unroll
    for (int s = 0; s < 5; ++s) { vA[s] = var_ids[(2*j)*5 + s]; vB[s] = var_ids[(2*j+1)*5 + s]; }
    const int op = op_ids[j];

    float ekA[5], ekB[5];
    const float e0A = __expf(lgl[pA]);
    const float e0B = __expf(lgl[pB]);
    float denA = e0A, denB = e0B;
#pragma unroll
    for (int s = 0; s < 5; ++s) {
        ekA[s] = __expf(lgl[VOCABSZ + vA[s]]); denA += ekA[s];
        ekB[s] = __expf(lgl[VOCABSZ + vB[s]]); denB += ekB[s];
    }
    const float invA = 1.0f / denA, invB = 1.0f / denB;
    const float batt = b_att[0];

    __half2 hA2[28], hB2[28];
    const float w0 = build_node(pA, vA, e0A, ekA, invA, batt, ldsraw, hA2);
    const float w2 = build_node(pB, vB, e0B, ekB, invB, batt, ldsraw, hB2);
    const float w1 = __expf(lgl[2*VOCABSZ + op]);
    const float inv2 = 1.0f / (w0 + w1 + w2);

    __syncthreads();                                        // B1: table reads done -> overlay

    // ---- write H row [tid][116] (hA|hB|zeros) + scalars ----
    {
        __half2* Hrow = (__half2*)ldsraw + tid*58;          // 116 halves
#pragma unroll
        for (int i = 0; i < 25; ++i) Hrow[i] = hA2[i];
#pragma unroll
        for (int i = 0; i < 25; ++i) Hrow[25+i] = hB2[i];
        const __half2 z = __floats2half2_rn(0.0f, 0.0f);
#pragma unroll
        for (int i = 50; i < 58; ++i) Hrow[i] = z;
        opl[tid] = op;
        w0l[tid] = w0*inv2; w2l[tid] = w2*inv2; w1l[tid] = w1*inv2;
    }
    // (no barrier: each wave reads only its own 64 rows/scalars below)

    const _Float16* Hp  = (const _Float16*)ldsraw;
    __half*         Hw  = (__half*)ldsraw;
    f32x4 C[4][4];

    // ---- P2: GEMM1  lin2[512x64] = H[512x116(100)] @ Wcat ----
    {
        const _Float16* Wcp = (const _Float16*)(ldsraw + LB_WC);
#pragma unroll
        for (int mt = 0; mt < 4; ++mt)
#pragma unroll
            for (int nt = 0; nt < 4; ++nt)
                C[mt][nt] = (f32x4){0.f, 0.f, 0.f, 0.f};
#pragma unroll
        for (int kk = 0; kk < 7; ++kk) {
            f16x4 bf[4];
#pragma unroll
            for (int nt = 0; nt < 4; ++nt)
                bf[nt] = *(const f16x4*)(Wcp + (nt*16 + lr)*116 + kk*16 + q*4);
#pragma unroll
            for (int mt = 0; mt < 4; ++mt) {
                f16x4 a = *(const f16x4*)(Hp + (w*64 + mt*16 + lr)*116 + kk*16 + q*4);
#pragma unroll
                for (int nt = 0; nt < 4; ++nt)
                    C[mt][nt] = __builtin_amdgcn_mfma_f32_16x16x16f16(a, bf[nt], C[mt][nt], 0, 0, 0);
            }
        }
        // epilogue: h_bin = relu(lin2 + Tb[op]) + w0i*hA + w2i*hB + w1i*oe[op]
        const __half2* TOg = (const __half2*)(wsh + H_TO);
#pragma unroll
        for (int mt = 0; mt < 4; ++mt)
#pragma unroll
            for (int nt = 0; nt < 4; ++nt) {
                const int d = nt*16 + lr;
#pragma unroll
                for (int r = 0; r < 4; ++r) {
                    const int node = w*64 + mt*16 + q*4 + r;
                    float v = 0.0f;
                    if (d < LDIM) {
                        const int opn = opl[node];
                        const float2 to = __half22float2(TOg[opn*LDIM + d]);   // {Tb, oe}
                        const float hA = __half2float(Hp[node*116 + d]);
                        const float hB = __half2float(Hp[node*116 + 50 + d]);
                        v = fmaxf(C[mt][nt][r] + to.x, 0.0f)
                          + w0l[node]*hA + w2l[node]*hB + w1l[node]*to.y;
                    }
                    C[mt][nt][r] = v;
                }
            }
    }
    __syncthreads();        // B2: stride-116 H reads done before stride-68 writes
#pragma unroll
    for (int mt = 0; mt < 4; ++mt)
#pragma unroll
        for (int nt = 0; nt < 4; ++nt) {
            const int d = nt*16 + lr;
#pragma unroll
            for (int r = 0; r < 4; ++r)
                Hw[(w*64 + mt*16 + q*4 + r)*68 + d] = __float2half(C[mt][nt][r]);
        }
    // (own-wave rows only -> no barrier)

    // ---- P3: GEMM2  h_un = relu(h_bin @ W_un + b_un) ----
    {
        const _Float16* Wup = (const _Float16*)(ldsraw + LB_WU);
#pragma unroll
        for (int mt = 0; mt < 4; ++mt)
#pragma unroll
            for (int nt = 0; nt < 4; ++nt)
                C[mt][nt] = (f32x4){0.f, 0.f, 0.f, 0.f};
#pragma unroll
        for (int kk = 0; kk < 4; ++kk) {
            f16x4 bf[4];
#pragma unroll
            for (int nt = 0; nt < 4; ++nt)
                bf[nt] = *(const f16x4*)(Wup + (nt*16 + lr)*68 + kk*16 + q*4);
#pragma unroll
            for (int mt = 0; mt < 4; ++mt) {
                f16x4 a = *(const f16x4*)(Hp + (w*64 + mt*16 + lr)*68 + kk*16 + q*4);
#pragma unroll
                for (int nt = 0; nt < 4; ++nt)
                    C[mt][nt] = __builtin_amdgcn_mfma_f32_16x16x16f16(a, bf[nt], C[mt][nt], 0, 0, 0);
            }
        }
    }
    __syncthreads();        // B3: GEMM2 done (Wc+Wu dead -> Wf overlay safe)
    {
        // write h_un (own rows) + stage W_finT cooperatively
#pragma unroll
        for (int mt = 0; mt < 4; ++mt)
#pragma unroll
            for (int nt = 0; nt < 4; ++nt) {
                const int d = nt*16 + lr;
#pragma unroll
                for (int r = 0; r < 4; ++r) {
                    const float v = (d < LDIM) ? fmaxf(C[mt][nt][r] + bul[d], 0.0f) : 0.0f;
                    Hw[(w*64 + mt*16 + q*4 + r)*68 + d] = __float2half(v);
                }
            }
        const uint2* sf = (const uint2*)(wsh + H_WF);
        uint2* df = (uint2*)(ldsraw + LB_WF);
        for (int i = tid; i < 2720; i += 512) df[i] = sf[i];
    }

    // ---- P4: GEMM3  h_q = relu(h_un @ W_univ + b_univ) ----
    {
        const _Float16* Wvp = (const _Float16*)(ldsraw + LB_WV);
#pragma unroll
        for (int mt = 0; mt < 4; ++mt)
#pragma unroll
            for (int nt = 0; nt < 4; ++nt)
                C[mt][nt] = (f32x4){0.f, 0.f, 0.f, 0.f};
#pragma unroll
        for (int kk = 0; kk < 4; ++kk) {
            f16x4 bf[4];
#pragma unroll
            for (int nt = 0; nt < 4; ++nt)
                bf[nt] = *(const f16x4*)(Wvp + (nt*16 + lr)*68 + kk*16 + q*4);
#pragma unroll
            for (int mt = 0; mt < 4; ++mt) {
                f16x4 a = *(const f16x4*)(Hp + (w*64 + mt*16 + lr)*68 + kk*16 + q*4);
#pragma unroll
                for (int nt = 0; nt < 4; ++nt)
                    C[mt][nt] = __builtin_amdgcn_mfma_f32_16x16x16f16(a, bf[nt], C[mt][nt], 0, 0, 0);
            }
        }
#pragma unroll
        for (int mt = 0; mt < 4; ++mt)
#pragma unroll
            for (int nt = 0; nt < 4; ++nt) {
                const int d = nt*16 + lr;
#pragma unroll
                for (int r = 0; r < 4; ++r) {
                    const float v = (d < LDIM) ? fmaxf(C[mt][nt][r] + bvl[d], 0.0f) : 0.0f;
                    Hw[(w*64 + mt*16 + q*4 + r)*68 + d] = __float2half(v);
                }
            }
    }
    __syncthreads();        // B5: GEMM3 done (Wv dead -> sw overlay safe; Wf staged)

    // ---- P5: GEMM4  out = h_q @ W_fin + b_fin  (LDS-transposed stores) ----
    {
        const _Float16* Wfp = (const _Float16*)(ldsraw + LB_WF);
        float* sww = (float*)(ldsraw + LB_SW) + w*272;      // 16x17 per wave
        for (int nt = 0; nt < 10; ++nt) {
            f16x4 bf[4];
#pragma unroll
            for (int kk = 0; kk < 4; ++kk)
                bf[kk] = *(const f16x4*)(Wfp + (nt*16 + lr)*68 + kk*16 + q*4);
            const int o = nt*16 + lr;
#pragma unroll
            for (int mt = 0; mt < 4; ++mt) {
                f32x4 c = (f32x4){0.f, 0.f, 0.f, 0.f};
#pragma unroll
                for (int kk = 0; kk < 4; ++kk) {
                    f16x4 a = *(const f16x4*)(Hp + (w*64 + mt*16 + lr)*68 + kk*16 + q*4);
                    c = __builtin_amdgcn_mfma_f32_16x16x16f16(a, bf[kk], c, 0, 0, 0);
                }
#pragma unroll
                for (int r = 0; r < 4; ++r)
                    sww[(q*4 + r)*17 + lr] = c[r] + ((o < ODIM) ? bfl[o] : 0.0f);
                float* gb = out + (size_t)(jbase + w*64 + mt*16) * ODIM + nt*16;
#pragma unroll
                for (int it = 0; it < 4; ++it) {
                    const int row = it*4 + q;
                    if (nt*16 + lr < ODIM)
                        gb[row*ODIM + lr] = sww[row*17 + lr];
                }
            }
        }
    }
}

// ---------------------------------------------------------------------------
extern "C" void kernel_launch(void* const* d_in, const int* in_sizes, int n_in,
                              void* d_out, int out_size, void* d_ws, size_t ws_size,
                              hipStream_t stream) {
    const float* pe     = (const float*)d_in[0];
    const float* ve     = (const float*)d_in[1];
    const float* oe     = (const float*)d_in[2];
    const float* W_pred = (const float*)d_in[3];
    const float* b_pred = (const float*)d_in[4];
    const float* W_bin  = (const float*)d_in[5];
    const float* b_bin  = (const float*)d_in[6];
    const float* W_un   = (const float*)d_in[7];
    const float* b_un   = (const float*)d_in[8];
    const float* W_univ = (const float*)d_in[9];
    const float* b_univ = (const float*)d_in[10];
    const float* W_att  = (const float*)d_in[11];
    const float* b_att  = (const float*)d_in[12];
    const float* W_fin  = (const float*)d_in[13];
    const float* b_fin  = (const float*)d_in[14];
    const int* pred_ids = (const int*)d_in[15];
    const int* var_ids  = (const int*)d_in[16];
    const int* op_ids   = (const int*)d_in[17];
    float* out = (float*)d_out;
    float* ws  = (float*)d_ws;

    precompute_kernel<<<181, 256, 0, stream>>>(pe, ve, oe, W_pred, b_pred,
                                               W_bin, b_bin, W_un, W_univ, W_fin,
                                               W_att, b_att, ws);
    fused_kernel<<<MBIN/512, 512, 0, stream>>>(W_att, b_att, b_un, b_univ, b_fin,
                                               pred_ids, var_ids, op_ids, ws, out);
}

// Round 14
// 322.913 us; speedup vs baseline: 7.8730x; 1.0376x over previous
//
#include <hip/hip_runtime.h>
#include <hip/hip_fp16.h>

#define LDIM 50
#define MBIN 262144
#define ODIM 155
#define VOCABSZ 100

typedef _Float16 f16x4 __attribute__((ext_vector_type(4)));
typedef _Float16 f16x2 __attribute__((ext_vector_type(2)));
typedef float    f32x4 __attribute__((ext_vector_type(4)));

// packed fp16 relu: v_pk_max_f16 with 0 (ROCm 7.2 header lacks __hmax2)
static __device__ __forceinline__ __half2 relu2(__half2 a) {
    f16x2 av; __builtin_memcpy(&av, &a, sizeof(av));
    const f16x2 zv = {(_Float16)0.0f, (_Float16)0.0f};
    f16x2 r = __builtin_elementwise_max(av, zv);
    __half2 out; __builtin_memcpy(&out, &r, sizeof(out));
    return out;
}

// ---- workspace half-offsets (from (__half*)ws) ----
// padded gather tables, row stride 56 halves (112 B, 16B-aligned):
//   rows 0..599   : T[s][v]  (s=0 pe-slot w/ b_pred; s=1..5 ve-slots)
//   rows 600..699 : pe
//   rows 700..799 : ve
#define H_TBL  0       // 800*56 = 44800 halves
#define H_TO   44800   // [100][50] half2 pairs {Tb, oe} -> 10000 halves
#define H_WC   54800   // WtCat  [64][116] : B^T of GEMM1 (zero-padded)
#define H_WU   62224   // W_unT  [64][68]
#define H_WV   66576   // W_univT[64][68]
#define H_WF   70928   // W_finT [160][68]  (ends 81808)
#define F_LG   40960   // float-offset: 300 attention logits fp32 (halves 81920..)

// ---- LDS byte offsets (static 161568 B) ----
// [0..89600) padded tables (build phase); H[512][116] fp16 overlays [0..118784)
#define LB_WC   118784   // 14848 B
#define LB_WU   133632   // 8704 B
#define LB_WV   142336   // 8704 B
#define LB_WF   118784   // overlays Wc+Wu after GEMM2 (21760 B)
#define LB_SW   140544   // 8 waves x 16x17 f32 (P5 only; overlays Wu/Wv tails)
#define LB_OP   151040
#define LB_W0   153088
#define LB_W2   155136
#define LB_W1   157184
#define LB_BU   159232
#define LB_BV   159432
#define LB_BF   159632
#define LB_LG   160256
#define LB_WATT 161456   // 28 half2 padded W_att (112 B)
#define LDS_BYTES 161568

// ---------------------------------------------------------------------------
// Precompute: 256-thr blocks, coalesced (round-12 proven, ~13 us)
// ---------------------------------------------------------------------------
__global__ __launch_bounds__(256) void precompute_kernel(
    const float* __restrict__ pe, const float* __restrict__ ve, const float* __restrict__ oe,
    const float* __restrict__ W_pred, const float* __restrict__ b_pred,
    const float* __restrict__ W_bin, const float* __restrict__ b_bin,
    const float* __restrict__ W_un, const float* __restrict__ W_univ,
    const float* __restrict__ W_fin,
    const float* __restrict__ W_att, const float* __restrict__ b_att,
    float* __restrict__ ws)
{
    __half* wsh = (__half*)ws;
    const int bid = blockIdx.x, tid = threadIdx.x;
    if (bid < 150) {                        // T tables: 4 rows/block, padded to 56
        const int row = bid*4 + (tid >> 6);          // 0..599
        const int t = tid & 63;
        const int s = row / VOCABSZ, v = row % VOCABSZ;
        if (t < 56) {
            float acc = 0.0f;
            if (t < 50) {
                acc = (s == 0) ? b_pred[t] : 0.0f;
                const float* E = (s == 0) ? pe : ve;
#pragma unroll
                for (int e = 0; e < 50; ++e)
                    acc += E[v*50 + e] * W_pred[(s*50 + e)*50 + t];
            }
            wsh[H_TBL + row*56 + t] = __float2half_rn(acc);
        }
    } else if (bid < 152) {                 // pe/ve padded fp16 copies
        const int which = bid - 150;        // 0: pe, 1: ve
        const float* E = which ? ve : pe;
        const int base = H_TBL + (600 + which*100) * 56;
        for (int idx = tid; idx < 5600; idx += 256) {
            const int r = idx / 56, c = idx % 56;
            wsh[base + idx] = __float2half_rn((c < 50) ? E[r*50 + c] : 0.0f);
        }
    } else if (bid < 177) {                 // TO = {Tb, oe} pairs: 4 v/block
        const int v = (bid - 152)*4 + (tid >> 6);
        const int t = tid & 63;
        if (t < 50) {
            float acc = b_bin[t];
#pragma unroll
            for (int e = 0; e < 50; ++e)
                acc += oe[v*50 + e] * W_bin[(50 + e)*50 + t];
            wsh[H_TO + (v*50 + t)*2]     = __float2half_rn(acc);
            wsh[H_TO + (v*50 + t)*2 + 1] = __float2half_rn(oe[v*50 + t]);
        }
    } else if (bid == 177) {                // WC [64][116]
        const int n = tid & 63, kc = tid >> 6;
        for (int k = kc*29; k < kc*29 + 29; ++k) {
            float val = 0.0f;
            if (n < 50) {
                if (k < 50)       val = W_bin[k*50 + n];
                else if (k < 100) val = W_bin[(100 + k - 50)*50 + n];
            }
            wsh[H_WC + n*116 + k] = __float2half_rn(val);
        }
    } else if (bid == 178) {                // WU + WV [64][68]
        const int n = tid & 63;
        const int half = tid >> 7;          // 0: WU, 1: WV
        const int kc = (tid >> 6) & 1;
        const float* W = half ? W_univ : W_un;
        const int base = half ? H_WV : H_WU;
        for (int k = kc*34; k < kc*34 + 34; ++k) {
            float val = (n < 50 && k < 50) ? W[k*50 + n] : 0.0f;
            wsh[base + n*68 + k] = __float2half_rn(val);
        }
    } else if (bid == 179) {                // WF [160][68]
        for (int idx = tid; idx < 10880; idx += 256) {
            const int n = idx % 160, k = idx / 160;
            float val = (n < ODIM && k < 50) ? W_fin[k*ODIM + n] : 0.0f;
            wsh[H_WF + n*68 + k] = __float2half_rn(val);
        }
    } else {                                // bid == 180: logits fp32
        for (int g = tid; g < 300; g += 256) {
            const int which = g / VOCABSZ, v = g % VOCABSZ;
            const float* E = (which == 0) ? pe : ((which == 1) ? ve : oe);
            float acc = b_att[0];
#pragma unroll
            for (int e = 0; e < 50; ++e)
                acc += E[v*50 + e] * W_att[e];
            ws[F_LG + g] = acc;
        }
    }
}

// ---------------------------------------------------------------------------
// Build one predicate node — ALL arithmetic in PACKED fp16 (v_pk_add/fma/max):
// no half->float conversions in the inner loop (round-12 lesson: P1 was
// VALU-inflated 3x by cvts, not LDS-bound). 12 uint4 loads + ~56 packed ops
// per 8-dim group. Returns the W_att logit partial (caller adds batt, exps).
// Pad dims 50..55 are exact zeros end-to-end.
// ---------------------------------------------------------------------------
__device__ __forceinline__ float build_node(
    int p, const int* __restrict__ v, __half2 e02, const __half2* __restrict__ ek2,
    __half2 invs, const char* __restrict__ ldsraw, __half2* __restrict__ h2out)
{
    const uint4* Tq = (const uint4*)ldsraw;       // row stride 7 uint4 (56 halves)
    const __half2* wattl = (const __half2*)(ldsraw + LB_WATT);
    const __half2 z2 = __floats2half2_rn(0.0f, 0.0f);
    __half2 lacc = z2;
#pragma unroll
    for (int g = 0; g < 7; ++g) {
        uint4 ul = Tq[p*7 + g];                   // T pred row (b_pred folded)
        uint4 up = Tq[(600 + p)*7 + g];           // pe row
        __half2 lin[4], num[4];
#pragma unroll
        for (int k = 0; k < 4; ++k) {
            lin[k] = ((const __half2*)&ul)[k];
            num[k] = __hmul2(e02, ((const __half2*)&up)[k]);
        }
#pragma unroll
        for (int s = 0; s < 5; ++s) {
            uint4 ua = Tq[((s+1)*VOCABSZ + v[s])*7 + g];   // T arg-slot row
            uint4 uv = Tq[(700 + v[s])*7 + g];             // ve row
#pragma unroll
            for (int k = 0; k < 4; ++k) {
                lin[k] = __hadd2(lin[k], ((const __half2*)&ua)[k]);
                num[k] = __hfma2(ek2[s], ((const __half2*)&uv)[k], num[k]);
            }
        }
#pragma unroll
        for (int k = 0; k < 4; ++k) {
            const __half2 h = __hfma2(num[k], invs, relu2(lin[k]));
            h2out[g*4 + k] = h;
            lacc = __hfma2(h, wattl[g*4 + k], lacc);
        }
    }
    return __low2float(lacc) + __high2float(lacc);
}

// ---------------------------------------------------------------------------
// Fused kernel (round-11/12 structure, proven): 512 thr, wave w owns 64 nodes.
// P1 packed-fp16 gather-build -> H[512][116] fp16 overlays tables ->
// GEMM1..4 on v_mfma_f32_16x16x16_f16 with pre-transposed fp16 weights.
// ---------------------------------------------------------------------------
__global__ __launch_bounds__(512)
void fused_kernel(
    const float* __restrict__ W_att, const float* __restrict__ b_att,
    const float* __restrict__ b_un, const float* __restrict__ b_univ,
    const float* __restrict__ b_fin,
    const int* __restrict__ pred_ids, const int* __restrict__ var_ids,
    const int* __restrict__ op_ids,
    const float* __restrict__ ws, float* __restrict__ out)
{
    __shared__ __align__(16) char ldsraw[LDS_BYTES];
    const __half* wsh = (const __half*)ws;
    const int tid = threadIdx.x;
    const int w = tid >> 6, l = tid & 63;
    const int lr = l & 15, q = l >> 4;
    const int jbase = blockIdx.x * 512;

    int*   opl = (int*)(ldsraw + LB_OP);
    float* w0l = (float*)(ldsraw + LB_W0);
    float* w2l = (float*)(ldsraw + LB_W2);
    float* w1l = (float*)(ldsraw + LB_W1);
    float* bul = (float*)(ldsraw + LB_BU);
    float* bvl = (float*)(ldsraw + LB_BV);
    float* bfl = (float*)(ldsraw + LB_BF);
    float* lgl = (float*)(ldsraw + LB_LG);

    // ---- P0: stage padded tables (89600B) + Wc/Wu/Wv + biases + lg + watt ----
    {
        const uint4* s = (const uint4*)wsh;                 // 5600 uint4
        uint4* d = (uint4*)ldsraw;
        for (int i = tid; i < 5600; i += 512) d[i] = s[i];
        const uint2* sc = (const uint2*)(wsh + H_WC);
        uint2* dc = (uint2*)(ldsraw + LB_WC);
        for (int i = tid; i < 1856; i += 512) dc[i] = sc[i];
        const uint2* su = (const uint2*)(wsh + H_WU);
        uint2* du = (uint2*)(ldsraw + LB_WU);
        for (int i = tid; i < 1088; i += 512) du[i] = su[i];
        const uint2* sv = (const uint2*)(wsh + H_WV);
        uint2* dv = (uint2*)(ldsraw + LB_WV);
        for (int i = tid; i < 1088; i += 512) dv[i] = sv[i];
        if (tid < 300) lgl[tid] = ws[F_LG + tid];
        if (tid < LDIM) { bul[tid] = b_un[tid]; bvl[tid] = b_univ[tid]; }
        if (tid < ODIM) bfl[tid] = b_fin[tid];
        if (tid >= 256 && tid < 284) {
            const int i = tid - 256;                        // half2 pair i -> dims 2i,2i+1
            const float x = (2*i < 50)   ? W_att[2*i]   : 0.0f;
            const float y = (2*i+1 < 50) ? W_att[2*i+1] : 0.0f;
            ((__half2*)(ldsraw + LB_WATT))[i] = __floats2half2_rn(x, y);
        }
    }
    __syncthreads();                                        // B0

    // ---- P1: packed-fp16 gather-build hA,hB + softmax scalars ----
    const int j = jbase + tid;
    int vA[5], vB[5];
    const int pA = pred_ids[2*j], pB = pred_ids[2*j+1];
#pragma unroll
    for (int s = 0; s < 5; ++s) { vA[s] = var_ids[(2*j)*5 + s]; vB[s] = var_ids[(2*j+1)*5 + s]; }
    const int op = op_ids[j];

    float ekA[5], ekB[5];
    const float e0A = __expf(lgl[pA]);
    const float e0B = __expf(lgl[pB]);
    float denA = e0A, denB = e0B;
#pragma unroll
    for (int s = 0; s < 5; ++s) {
        ekA[s] = __expf(lgl[VOCABSZ + vA[s]]); denA += ekA[s];
        ekB[s] = __expf(lgl[VOCABSZ + vB[s]]); denB += ekB[s];
    }
    const float invA = 1.0f / denA, invB = 1.0f / denB;
    const float batt = b_att[0];

    __half2 ek2A[5], ek2B[5];
#pragma unroll
    for (int s = 0; s < 5; ++s) {
        ek2A[s] = __float2half2_rn(ekA[s]);
        ek2B[s] = __float2half2_rn(ekB[s]);
    }

    __half2 hA2[28], hB2[28];
    const float w0 = __expf(batt + build_node(pA, vA, __float2half2_rn(e0A), ek2A,
                                              __float2half2_rn(invA), ldsraw, hA2));
    const float w2 = __expf(batt + build_node(pB, vB, __float2half2_rn(e0B), ek2B,
                                              __float2half2_rn(invB), ldsraw, hB2));
    const float w1 = __expf(lgl[2*VOCABSZ + op]);
    const float inv2 = 1.0f / (w0 + w1 + w2);

    __syncthreads();                                        // B1: table reads done -> overlay

    // ---- write H row [tid][116] (hA|hB|zeros) + scalars ----
    {
        __half2* Hrow = (__half2*)ldsraw + tid*58;          // 116 halves
#pragma unroll
        for (int i = 0; i < 25; ++i) Hrow[i] = hA2[i];
#pragma unroll
        for (int i = 0; i < 25; ++i) Hrow[25+i] = hB2[i];
        const __half2 z = __floats2half2_rn(0.0f, 0.0f);
#pragma unroll
        for (int i = 50; i < 58; ++i) Hrow[i] = z;
        opl[tid] = op;
        w0l[tid] = w0*inv2; w2l[tid] = w2*inv2; w1l[tid] = w1*inv2;
    }
    // (no barrier: each wave reads only its own 64 rows/scalars below)

    const _Float16* Hp  = (const _Float16*)ldsraw;
    __half*         Hw  = (__half*)ldsraw;
    f32x4 C[4][4];

    // ---- P2: GEMM1  lin2[512x64] = H[512x116(100)] @ Wcat ----
    {
        const _Float16* Wcp = (const _Float16*)(ldsraw + LB_WC);
#pragma unroll
        for (int mt = 0; mt < 4; ++mt)
#pragma unroll
            for (int nt = 0; nt < 4; ++nt)
                C[mt][nt] = (f32x4){0.f, 0.f, 0.f, 0.f};
#pragma unroll
        for (int kk = 0; kk < 7; ++kk) {
            f16x4 bf[4];
#pragma unroll
            for (int nt = 0; nt < 4; ++nt)
                bf[nt] = *(const f16x4*)(Wcp + (nt*16 + lr)*116 + kk*16 + q*4);
#pragma unroll
            for (int mt = 0; mt < 4; ++mt) {
                f16x4 a = *(const f16x4*)(Hp + (w*64 + mt*16 + lr)*116 + kk*16 + q*4);
#pragma unroll
                for (int nt = 0; nt < 4; ++nt)
                    C[mt][nt] = __builtin_amdgcn_mfma_f32_16x16x16f16(a, bf[nt], C[mt][nt], 0, 0, 0);
            }
        }
        // epilogue: h_bin = relu(lin2 + Tb[op]) + w0i*hA + w2i*hB + w1i*oe[op]
        const __half2* TOg = (const __half2*)(wsh + H_TO);
#pragma unroll
        for (int mt = 0; mt < 4; ++mt)
#pragma unroll
            for (int nt = 0; nt < 4; ++nt) {
                const int d = nt*16 + lr;
#pragma unroll
                for (int r = 0; r < 4; ++r) {
                    const int node = w*64 + mt*16 + q*4 + r;
                    float v = 0.0f;
                    if (d < LDIM) {
                        const int opn = opl[node];
                        const float2 to = __half22float2(TOg[opn*LDIM + d]);   // {Tb, oe}
                        const float hA = __half2float(Hp[node*116 + d]);
                        const float hB = __half2float(Hp[node*116 + 50 + d]);
                        v = fmaxf(C[mt][nt][r] + to.x, 0.0f)
                          + w0l[node]*hA + w2l[node]*hB + w1l[node]*to.y;
                    }
                    C[mt][nt][r] = v;
                }
            }
    }
    __syncthreads();        // B2: stride-116 H reads done before stride-68 writes
#pragma unroll
    for (int mt = 0; mt < 4; ++mt)
#pragma unroll
        for (int nt = 0; nt < 4; ++nt) {
            const int d = nt*16 + lr;
#pragma unroll
            for (int r = 0; r < 4; ++r)
                Hw[(w*64 + mt*16 + q*4 + r)*68 + d] = __float2half(C[mt][nt][r]);
        }
    // (own-wave rows only -> no barrier)

    // ---- P3: GEMM2  h_un = relu(h_bin @ W_un + b_un) ----
    {
        const _Float16* Wup = (const _Float16*)(ldsraw + LB_WU);
#pragma unroll
        for (int mt = 0; mt < 4; ++mt)
#pragma unroll
            for (int nt = 0; nt < 4; ++nt)
                C[mt][nt] = (f32x4){0.f, 0.f, 0.f, 0.f};
#pragma unroll
        for (int kk = 0; kk < 4; ++kk) {
            f16x4 bf[4];
#pragma unroll
            for (int nt = 0; nt < 4; ++nt)
                bf[nt] = *(const f16x4*)(Wup + (nt*16 + lr)*68 + kk*16 + q*4);
#pragma unroll
            for (int mt = 0; mt < 4; ++mt) {
                f16x4 a = *(const f16x4*)(Hp + (w*64 + mt*16 + lr)*68 + kk*16 + q*4);
#pragma unroll
                for (int nt = 0; nt < 4; ++nt)
                    C[mt][nt] = __builtin_amdgcn_mfma_f32_16x16x16f16(a, bf[nt], C[mt][nt], 0, 0, 0);
            }
        }
    }
    __syncthreads();        // B3: GEMM2 done (Wc+Wu dead -> Wf overlay safe)
    {
        // write h_un (own rows) + stage W_finT cooperatively
#pragma unroll
        for (int mt = 0; mt < 4; ++mt)
#pragma unroll
            for (int nt = 0; nt < 4; ++nt) {
                const int d = nt*16 + lr;
#pragma unroll
                for (int r = 0; r < 4; ++r) {
                    const float v = (d < LDIM) ? fmaxf(C[mt][nt][r] + bul[d], 0.0f) : 0.0f;
                    Hw[(w*64 + mt*16 + q*4 + r)*68 + d] = __float2half(v);
                }
            }
        const uint2* sf = (const uint2*)(wsh + H_WF);
        uint2* df = (uint2*)(ldsraw + LB_WF);
        for (int i = tid; i < 2720; i += 512) df[i] = sf[i];
    }

    // ---- P4: GEMM3  h_q = relu(h_un @ W_univ + b_univ) ----
    {
        const _Float16* Wvp = (const _Float16*)(ldsraw + LB_WV);
#pragma unroll
        for (int mt = 0; mt < 4; ++mt)
#pragma unroll
            for (int nt = 0; nt < 4; ++nt)
                C[mt][nt] = (f32x4){0.f, 0.f, 0.f, 0.f};
#pragma unroll
        for (int kk = 0; kk < 4; ++kk) {
            f16x4 bf[4];
#pragma unroll
            for (int nt = 0; nt < 4; ++nt)
                bf[nt] = *(const f16x4*)(Wvp + (nt*16 + lr)*68 + kk*16 + q*4);
#pragma unroll
            for (int mt = 0; mt < 4; ++mt) {
                f16x4 a = *(const f16x4*)(Hp + (w*64 + mt*16 + lr)*68 + kk*16 + q*4);
#pragma unroll
                for (int nt = 0; nt < 4; ++nt)
                    C[mt][nt] = __builtin_amdgcn_mfma_f32_16x16x16f16(a, bf[nt], C[mt][nt], 0, 0, 0);
            }
        }
#pragma unroll
        for (int mt = 0; mt < 4; ++mt)
#pragma unroll
            for (int nt = 0; nt < 4; ++nt) {
                const int d = nt*16 + lr;
#pragma unroll
                for (int r = 0; r < 4; ++r) {
                    const float v = (d < LDIM) ? fmaxf(C[mt][nt][r] + bvl[d], 0.0f) : 0.0f;
                    Hw[(w*64 + mt*16 + q*4 + r)*68 + d] = __float2half(v);
                }
            }
    }
    __syncthreads();        // B5: GEMM3 done (Wv dead -> sw overlay safe; Wf staged)

    // ---- P5: GEMM4  out = h_q @ W_fin + b_fin  (LDS-transposed stores) ----
    {
        const _Float16* Wfp = (const _Float16*)(ldsraw + LB_WF);
        float* sww = (float*)(ldsraw + LB_SW) + w*272;      // 16x17 per wave
        for (int nt = 0; nt < 10; ++nt) {
            f16x4 bf[4];
#pragma unroll
            for (int kk = 0; kk < 4; ++kk)
                bf[kk] = *(const f16x4*)(Wfp + (nt*16 + lr)*68 + kk*16 + q*4);
            const int o = nt*16 + lr;
#pragma unroll
            for (int mt = 0; mt < 4; ++mt) {
                f32x4 c = (f32x4){0.f, 0.f, 0.f, 0.f};
#pragma unroll
                for (int kk = 0; kk < 4; ++kk) {
                    f16x4 a = *(const f16x4*)(Hp + (w*64 + mt*16 + lr)*68 + kk*16 + q*4);
                    c = __builtin_amdgcn_mfma_f32_16x16x16f16(a, bf[kk], c, 0, 0, 0);
                }
#pragma unroll
                for (int r = 0; r < 4; ++r)
                    sww[(q*4 + r)*17 + lr] = c[r] + ((o < ODIM) ? bfl[o] : 0.0f);
                float* gb = out + (size_t)(jbase + w*64 + mt*16) * ODIM + nt*16;
#pragma unroll
                for (int it = 0; it < 4; ++it) {
                    const int row = it*4 + q;
                    if (nt*16 + lr < ODIM)
                        gb[row*ODIM + lr] = sww[row*17 + lr];
                }
            }
        }
    }
}

// ---------------------------------------------------------------------------
extern "C" void kernel_launch(void* const* d_in, const int* in_sizes, int n_in,
                              void* d_out, int out_size, void* d_ws, size_t ws_size,
                              hipStream_t stream) {
    const float* pe     = (const float*)d_in[0];
    const float* ve     = (const float*)d_in[1];
    const float* oe     = (const float*)d_in[2];
    const float* W_pred = (const float*)d_in[3];
    const float* b_pred = (const float*)d_in[4];
    const float* W_bin  = (const float*)d_in[5];
    const float* b_bin  = (const float*)d_in[6];
    const float* W_un   = (const float*)d_in[7];
    const float* b_un   = (const float*)d_in[8];
    const float* W_univ = (const float*)d_in[9];
    const float* b_univ = (const float*)d_in[10];
    const float* W_att  = (const float*)d_in[11];
    const float* b_att  = (const float*)d_in[12];
    const float* W_fin  = (const float*)d_in[13];
    const float* b_fin  = (const float*)d_in[14];
    const int* pred_ids = (const int*)d_in[15];
    const int* var_ids  = (const int*)d_in[16];
    const int* op_ids   = (const int*)d_in[17];
    float* out = (float*)d_out;
    float* ws  = (float*)d_ws;

    precompute_kernel<<<181, 256, 0, stream>>>(pe, ve, oe, W_pred, b_pred,
                                               W_bin, b_bin, W_un, W_univ, W_fin,
                                               W_att, b_att, ws);
    fused_kernel<<<MBIN/512, 512, 0, stream>>>(W_att, b_att, b_un, b_univ, b_fin,
                                               pred_ids, var_ids, op_ids, ws, out);
}

// Round 15
// 311.445 us; speedup vs baseline: 8.1628x; 1.0368x over previous
//
#include <hip/hip_runtime.h>
#include <hip/hip_fp16.h>

#define LDIM 50
#define MBIN 262144
#define ODIM 155
#define VOCABSZ 100

typedef _Float16 f16x4 __attribute__((ext_vector_type(4)));
typedef _Float16 f16x2 __attribute__((ext_vector_type(2)));
typedef float    f32x4 __attribute__((ext_vector_type(4)));

// packed fp16 relu: v_pk_max_f16 with 0 (ROCm 7.2 header lacks __hmax2)
static __device__ __forceinline__ __half2 relu2(__half2 a) {
    f16x2 av; __builtin_memcpy(&av, &a, sizeof(av));
    const f16x2 zv = {(_Float16)0.0f, (_Float16)0.0f};
    f16x2 r = __builtin_elementwise_max(av, zv);
    __half2 out; __builtin_memcpy(&out, &r, sizeof(out));
    return out;
}

// ---- workspace half-offsets (from (__half*)ws) — same as round 14 ----
#define H_TBL  0       // 800*56 halves padded gather tables (T|pe|ve)
#define H_TO   44800   // [100][50] half2 pairs {Tb, oe}
#define H_WC   54800   // WtCat  [64][116]
#define H_WU   62224   // W_unT  [64][68]
#define H_WV   66576   // W_univT[64][68]
#define H_WF   70928   // W_finT [160][68]
#define F_LG   40960   // float-offset: 300 attention logits fp32

// ---- LDS byte offsets: TOTAL 72640 B -> 2 blocks/CU (16 waves) target ----
// per-wave chunk slab: [16][116] fp16 (232B rows); sww overlays bytes 128..196
#define LB_SLAB 0        // 8 waves x 3712 = 29696
#define LB_WC   29696    // 14848
#define LB_WU   44544    // 8704
#define LB_WV   53248    // 8704
#define LB_OP   61952    // 512 int
#define LB_W0   64000
#define LB_W2   66048
#define LB_W1   68096
#define LB_BU   70144
#define LB_BV   70400
#define LB_BF   70656
#define LB_LG   71296
#define LB_WATT 72512
#define LDS_BYTES 72640

// ---------------------------------------------------------------------------
// Precompute: identical to round 14 (proven, ~13 us)
// ---------------------------------------------------------------------------
__global__ __launch_bounds__(256) void precompute_kernel(
    const float* __restrict__ pe, const float* __restrict__ ve, const float* __restrict__ oe,
    const float* __restrict__ W_pred, const float* __restrict__ b_pred,
    const float* __restrict__ W_bin, const float* __restrict__ b_bin,
    const float* __restrict__ W_un, const float* __restrict__ W_univ,
    const float* __restrict__ W_fin,
    const float* __restrict__ W_att, const float* __restrict__ b_att,
    float* __restrict__ ws)
{
    __half* wsh = (__half*)ws;
    const int bid = blockIdx.x, tid = threadIdx.x;
    if (bid < 150) {
        const int row = bid*4 + (tid >> 6);
        const int t = tid & 63;
        const int s = row / VOCABSZ, v = row % VOCABSZ;
        if (t < 56) {
            float acc = 0.0f;
            if (t < 50) {
                acc = (s == 0) ? b_pred[t] : 0.0f;
                const float* E = (s == 0) ? pe : ve;
#pragma unroll
                for (int e = 0; e < 50; ++e)
                    acc += E[v*50 + e] * W_pred[(s*50 + e)*50 + t];
            }
            wsh[H_TBL + row*56 + t] = __float2half_rn(acc);
        }
    } else if (bid < 152) {
        const int which = bid - 150;
        const float* E = which ? ve : pe;
        const int base = H_TBL + (600 + which*100) * 56;
        for (int idx = tid; idx < 5600; idx += 256) {
            const int r = idx / 56, c = idx % 56;
            wsh[base + idx] = __float2half_rn((c < 50) ? E[r*50 + c] : 0.0f);
        }
    } else if (bid < 177) {
        const int v = (bid - 152)*4 + (tid >> 6);
        const int t = tid & 63;
        if (t < 50) {
            float acc = b_bin[t];
#pragma unroll
            for (int e = 0; e < 50; ++e)
                acc += oe[v*50 + e] * W_bin[(50 + e)*50 + t];
            wsh[H_TO + (v*50 + t)*2]     = __float2half_rn(acc);
            wsh[H_TO + (v*50 + t)*2 + 1] = __float2half_rn(oe[v*50 + t]);
        }
    } else if (bid == 177) {
        const int n = tid & 63, kc = tid >> 6;
        for (int k = kc*29; k < kc*29 + 29; ++k) {
            float val = 0.0f;
            if (n < 50) {
                if (k < 50)       val = W_bin[k*50 + n];
                else if (k < 100) val = W_bin[(100 + k - 50)*50 + n];
            }
            wsh[H_WC + n*116 + k] = __float2half_rn(val);
        }
    } else if (bid == 178) {
        const int n = tid & 63;
        const int half = tid >> 7;
        const int kc = (tid >> 6) & 1;
        const float* W = half ? W_univ : W_un;
        const int base = half ? H_WV : H_WU;
        for (int k = kc*34; k < kc*34 + 34; ++k) {
            float val = (n < 50 && k < 50) ? W[k*50 + n] : 0.0f;
            wsh[base + n*68 + k] = __float2half_rn(val);
        }
    } else if (bid == 179) {
        for (int idx = tid; idx < 10880; idx += 256) {
            const int n = idx % 160, k = idx / 160;
            float val = (n < ODIM && k < 50) ? W_fin[k*ODIM + n] : 0.0f;
            wsh[H_WF + n*68 + k] = __float2half_rn(val);
        }
    } else {
        for (int g = tid; g < 300; g += 256) {
            const int which = g / VOCABSZ, v = g % VOCABSZ;
            const float* E = (which == 0) ? pe : ((which == 1) ? ve : oe);
            float acc = b_att[0];
#pragma unroll
            for (int e = 0; e < 50; ++e)
                acc += E[v*50 + e] * W_att[e];
            ws[F_LG + g] = acc;
        }
    }
}

// ---------------------------------------------------------------------------
// Build one predicate node — packed fp16 (round-14 proven math), tables read
// from GLOBAL (L2-resident 90KB; 12-deep load ILP hides ~200cyc latency).
// ---------------------------------------------------------------------------
__device__ __forceinline__ float build_node(
    int p, const int* __restrict__ v, __half2 e02, const __half2* __restrict__ ek2,
    __half2 invs, const uint4* __restrict__ tq, const __half2* __restrict__ wattl,
    __half2* __restrict__ h2out)
{
    const __half2 z2 = __floats2half2_rn(0.0f, 0.0f);
    __half2 lacc = z2;
#pragma unroll
    for (int g = 0; g < 7; ++g) {
        uint4 ul = tq[p*7 + g];                   // T pred row (b_pred folded)
        uint4 up = tq[(600 + p)*7 + g];           // pe row
        __half2 lin[4], num[4];
#pragma unroll
        for (int k = 0; k < 4; ++k) {
            lin[k] = ((const __half2*)&ul)[k];
            num[k] = __hmul2(e02, ((const __half2*)&up)[k]);
        }
#pragma unroll
        for (int s = 0; s < 5; ++s) {
            uint4 ua = tq[((s+1)*VOCABSZ + v[s])*7 + g];   // T arg-slot row
            uint4 uv = tq[(700 + v[s])*7 + g];             // ve row
#pragma unroll
            for (int k = 0; k < 4; ++k) {
                lin[k] = __hadd2(lin[k], ((const __half2*)&ua)[k]);
                num[k] = __hfma2(ek2[s], ((const __half2*)&uv)[k], num[k]);
            }
        }
#pragma unroll
        for (int k = 0; k < 4; ++k) {
            const __half2 h = __hfma2(num[k], invs, relu2(lin[k]));
            h2out[g*4 + k] = h;
            lacc = __hfma2(h, wattl[g*4 + k], lacc);
        }
    }
    return __low2float(lacc) + __high2float(lacc);
}

// ---------------------------------------------------------------------------
// Fused kernel v2: 512 thr, wave w owns 64 nodes; NO block barriers after P0.
// Gather from global L2 (tables out of LDS) -> LDS = 72.6KB -> 2 blocks/CU.
// Each wave free-runs: build 64 nodes (h in 56 VGPRs) then 4 chunks of 16:
// {write [16][116] slab -> GEMM1(Wc,LDS) -> epilogue -> GEMM2(Wu) ->
//  GEMM3(Wv) -> GEMM4(Wf from global) -> transposed stores}. All slab traffic
// is wave-private (within-wave LDS ordering, no barriers).
// ---------------------------------------------------------------------------
__global__ __launch_bounds__(512)
void fused_kernel(
    const float* __restrict__ W_att, const float* __restrict__ b_att,
    const float* __restrict__ b_un, const float* __restrict__ b_univ,
    const float* __restrict__ b_fin,
    const int* __restrict__ pred_ids, const int* __restrict__ var_ids,
    const int* __restrict__ op_ids,
    const float* __restrict__ ws, float* __restrict__ out)
{
    __shared__ __align__(16) char ldsraw[LDS_BYTES];
    const __half* wsh = (const __half*)ws;
    const int tid = threadIdx.x;
    const int w = tid >> 6, l = tid & 63;
    const int lr = l & 15, q = l >> 4;
    const int jbase = blockIdx.x * 512;

    int*   opl = (int*)(ldsraw + LB_OP);
    float* w0l = (float*)(ldsraw + LB_W0);
    float* w2l = (float*)(ldsraw + LB_W2);
    float* w1l = (float*)(ldsraw + LB_W1);
    float* bul = (float*)(ldsraw + LB_BU);
    float* bvl = (float*)(ldsraw + LB_BV);
    float* bfl = (float*)(ldsraw + LB_BF);
    float* lgl = (float*)(ldsraw + LB_LG);

    // ---- P0: stage Wc/Wu/Wv + scalars (tables stay in global/L2) ----
    {
        const uint4* sc = (const uint4*)(wsh + H_WC);       // 928 uint4
        uint4* dc = (uint4*)(ldsraw + LB_WC);
        for (int i = tid; i < 928; i += 512) dc[i] = sc[i];
        const uint4* su = (const uint4*)(wsh + H_WU);       // 544
        uint4* du = (uint4*)(ldsraw + LB_WU);
        for (int i = tid; i < 544; i += 512) du[i] = su[i];
        const uint4* sv = (const uint4*)(wsh + H_WV);       // 544
        uint4* dv = (uint4*)(ldsraw + LB_WV);
        for (int i = tid; i < 544; i += 512) dv[i] = sv[i];
        if (tid < 300) lgl[tid] = ws[F_LG + tid];
        if (tid < LDIM) { bul[tid] = b_un[tid]; bvl[tid] = b_univ[tid]; }
        if (tid < ODIM) bfl[tid] = b_fin[tid];
        if (tid >= 256 && tid < 284) {
            const int i = tid - 256;
            const float x = (2*i < 50)   ? W_att[2*i]   : 0.0f;
            const float y = (2*i+1 < 50) ? W_att[2*i+1] : 0.0f;
            ((__half2*)(ldsraw + LB_WATT))[i] = __floats2half2_rn(x, y);
        }
    }
    __syncthreads();                                        // B0 (the only barrier)

    // ---- P1: packed-fp16 gather-build from GLOBAL tables ----
    const int j = jbase + tid;
    int vA[5], vB[5];
    const int pA = pred_ids[2*j], pB = pred_ids[2*j+1];
#pragma unroll
    for (int s = 0; s < 5; ++s) { vA[s] = var_ids[(2*j)*5 + s]; vB[s] = var_ids[(2*j+1)*5 + s]; }
    const int op = op_ids[j];

    float ekA[5], ekB[5];
    const float e0A = __expf(lgl[pA]);
    const float e0B = __expf(lgl[pB]);
    float denA = e0A, denB = e0B;
#pragma unroll
    for (int s = 0; s < 5; ++s) {
        ekA[s] = __expf(lgl[VOCABSZ + vA[s]]); denA += ekA[s];
        ekB[s] = __expf(lgl[VOCABSZ + vB[s]]); denB += ekB[s];
    }
    const float invA = 1.0f / denA, invB = 1.0f / denB;
    const float batt = b_att[0];

    __half2 ek2A[5], ek2B[5];
#pragma unroll
    for (int s = 0; s < 5; ++s) {
        ek2A[s] = __float2half2_rn(ekA[s]);
        ek2B[s] = __float2half2_rn(ekB[s]);
    }

    const uint4* tq = (const uint4*)wsh;                    // padded tables, global
    const __half2* wattl = (const __half2*)(ldsraw + LB_WATT);

    __half2 hA2[28], hB2[28];
    const float w0 = __expf(batt + build_node(pA, vA, __float2half2_rn(e0A), ek2A,
                                              __float2half2_rn(invA), tq, wattl, hA2));
    const float w2 = __expf(batt + build_node(pB, vB, __float2half2_rn(e0B), ek2B,
                                              __float2half2_rn(invB), tq, wattl, hB2));
    const float w1 = __expf(lgl[2*VOCABSZ + op]);
    const float inv2 = 1.0f / (w0 + w1 + w2);

    // publish per-node scalars (consumed only by own wave -> no barrier)
    opl[tid] = op;
    w0l[tid] = w0*inv2; w2l[tid] = w2*inv2; w1l[tid] = w1*inv2;

    char* slab = ldsraw + LB_SLAB + w*3712;                 // [16][116] fp16, 232B rows
    const __half2* TOg = (const __half2*)(wsh + H_TO);
    const _Float16* Wcp = (const _Float16*)(ldsraw + LB_WC);
    const _Float16* Wup = (const _Float16*)(ldsraw + LB_WU);
    const _Float16* Wvp = (const _Float16*)(ldsraw + LB_WV);
    const _Float16* Wfg = (const _Float16*)(wsh + H_WF);    // global, L2-hot

    for (int c = 0; c < 4; ++c) {
        // ---- owner lanes write chunk H rows [hA|hB|zeros] ----
        if ((l >> 4) == c) {
            uint* dst = (uint*)(slab + (l & 15)*232);
#pragma unroll
            for (int i = 0; i < 25; ++i) { uint u; __builtin_memcpy(&u, &hA2[i], 4); dst[i] = u; }
#pragma unroll
            for (int i = 0; i < 25; ++i) { uint u; __builtin_memcpy(&u, &hB2[i], 4); dst[25+i] = u; }
#pragma unroll
            for (int i = 50; i < 58; ++i) dst[i] = 0u;
        }

        // ---- GEMM1: lin2[16x64] = H[16x116(100)] @ Wcat ----
        f32x4 C1[4];
#pragma unroll
        for (int nt = 0; nt < 4; ++nt) C1[nt] = (f32x4){0.f, 0.f, 0.f, 0.f};
#pragma unroll
        for (int kk = 0; kk < 7; ++kk) {
            f16x4 a = *(const f16x4*)(slab + lr*232 + kk*32 + q*8);
#pragma unroll
            for (int nt = 0; nt < 4; ++nt) {
                f16x4 b = *(const f16x4*)((const char*)Wcp + (nt*16 + lr)*232 + kk*32 + q*8);
                C1[nt] = __builtin_amdgcn_mfma_f32_16x16x16f16(a, b, C1[nt], 0, 0, 0);
            }
        }
        // epilogue: h_bin = relu(lin2 + Tb[op]) + w0i*hA + w2i*hB + w1i*oe[op]
        {
            const __half* sh = (const __half*)slab;
            const int cb = c*16;
#pragma unroll
            for (int nt = 0; nt < 4; ++nt) {
                const int d = nt*16 + lr;
#pragma unroll
                for (int r = 0; r < 4; ++r) {
                    float v = 0.0f;
                    if (d < LDIM) {
                        const int nw = w*64 + cb + q*4 + r;
                        const int opn = opl[nw];
                        const float2 to = __half22float2(TOg[opn*LDIM + d]);   // {Tb, oe}
                        const float hAv = __half2float(sh[(q*4 + r)*116 + d]);
                        const float hBv = __half2float(sh[(q*4 + r)*116 + 50 + d]);
                        v = fmaxf(C1[nt][r] + to.x, 0.0f)
                          + w0l[nw]*hAv + w2l[nw]*hBv + w1l[nw]*to.y;
                    }
                    C1[nt][r] = v;
                }
            }
            // all reads done -> write h_bin into slab cols 0..63 (zeros d>=50)
            __half* shw = (__half*)slab;
#pragma unroll
            for (int nt = 0; nt < 4; ++nt)
#pragma unroll
                for (int r = 0; r < 4; ++r)
                    shw[(q*4 + r)*116 + nt*16 + lr] = __float2half(C1[nt][r]);
        }

        // ---- GEMM2: h_un = relu(h_bin @ W_un + b_un) ----
        {
            f32x4 C2[4];
#pragma unroll
            for (int nt = 0; nt < 4; ++nt) C2[nt] = (f32x4){0.f, 0.f, 0.f, 0.f};
#pragma unroll
            for (int kk = 0; kk < 4; ++kk) {
                f16x4 a = *(const f16x4*)(slab + lr*232 + kk*32 + q*8);
#pragma unroll
                for (int nt = 0; nt < 4; ++nt) {
                    f16x4 b = *(const f16x4*)((const char*)Wup + (nt*16 + lr)*136 + kk*32 + q*8);
                    C2[nt] = __builtin_amdgcn_mfma_f32_16x16x16f16(a, b, C2[nt], 0, 0, 0);
                }
            }
            __half* shw = (__half*)slab;
#pragma unroll
            for (int nt = 0; nt < 4; ++nt) {
                const int d = nt*16 + lr;
#pragma unroll
                for (int r = 0; r < 4; ++r) {
                    const float v = (d < LDIM) ? fmaxf(C2[nt][r] + bul[d], 0.0f) : 0.0f;
                    shw[(q*4 + r)*116 + d] = __float2half(v);
                }
            }
        }

        // ---- GEMM3: h_q = relu(h_un @ W_univ + b_univ) ----
        {
            f32x4 C3[4];
#pragma unroll
            for (int nt = 0; nt < 4; ++nt) C3[nt] = (f32x4){0.f, 0.f, 0.f, 0.f};
#pragma unroll
            for (int kk = 0; kk < 4; ++kk) {
                f16x4 a = *(const f16x4*)(slab + lr*232 + kk*32 + q*8);
#pragma unroll
                for (int nt = 0; nt < 4; ++nt) {
                    f16x4 b = *(const f16x4*)((const char*)Wvp + (nt*16 + lr)*136 + kk*32 + q*8);
                    C3[nt] = __builtin_amdgcn_mfma_f32_16x16x16f16(a, b, C3[nt], 0, 0, 0);
                }
            }
            __half* shw = (__half*)slab;
#pragma unroll
            for (int nt = 0; nt < 4; ++nt) {
                const int d = nt*16 + lr;
#pragma unroll
                for (int r = 0; r < 4; ++r) {
                    const float v = (d < LDIM) ? fmaxf(C3[nt][r] + bvl[d], 0.0f) : 0.0f;
                    shw[(q*4 + r)*116 + d] = __float2half(v);
                }
            }
        }

        // ---- GEMM4: out = h_q @ W_fin + b_fin (B from global L2) ----
        // sww transpose buffer embedded in slab bytes [row*232+128 .. +196)
        {
            float* gb = out + (size_t)(jbase + w*64 + c*16) * ODIM;
            for (int nt = 0; nt < 10; ++nt) {
                f16x4 bf[4];
#pragma unroll
                for (int kk = 0; kk < 4; ++kk)
                    bf[kk] = *(const f16x4*)((const char*)Wfg + (nt*16 + lr)*136 + kk*32 + q*8);
                f32x4 c4 = (f32x4){0.f, 0.f, 0.f, 0.f};
#pragma unroll
                for (int kk = 0; kk < 4; ++kk) {
                    f16x4 a = *(const f16x4*)(slab + lr*232 + kk*32 + q*8);
                    c4 = __builtin_amdgcn_mfma_f32_16x16x16f16(a, bf[kk], c4, 0, 0, 0);
                }
                const int o = nt*16 + lr;
                const float bv = (o < ODIM) ? bfl[o] : 0.0f;
#pragma unroll
                for (int r = 0; r < 4; ++r)
                    *(float*)(slab + (q*4 + r)*232 + 128 + lr*4) = c4[r] + bv;
#pragma unroll
                for (int it = 0; it < 4; ++it) {
                    const int row = it*4 + q;
                    if (o < ODIM)
                        gb[row*ODIM + nt*16 + lr] =
                            *(const float*)(slab + row*232 + 128 + lr*4);
                }
            }
        }
    }
}

// ---------------------------------------------------------------------------
extern "C" void kernel_launch(void* const* d_in, const int* in_sizes, int n_in,
                              void* d_out, int out_size, void* d_ws, size_t ws_size,
                              hipStream_t stream) {
    const float* pe     = (const float*)d_in[0];
    const float* ve     = (const float*)d_in[1];
    const float* oe     = (const float*)d_in[2];
    const float* W_pred = (const float*)d_in[3];
    const float* b_pred = (const float*)d_in[4];
    const float* W_bin  = (const float*)d_in[5];
    const float* b_bin  = (const float*)d_in[6];
    const float* W_un   = (const float*)d_in[7];
    const float* b_un   = (const float*)d_in[8];
    const float* W_univ = (const float*)d_in[9];
    const float* b_univ = (const float*)d_in[10];
    const float* W_att  = (const float*)d_in[11];
    const float* b_att  = (const float*)d_in[12];
    const float* W_fin  = (const float*)d_in[13];
    const float* b_fin  = (const float*)d_in[14];
    const int* pred_ids = (const int*)d_in[15];
    const int* var_ids  = (const int*)d_in[16];
    const int* op_ids   = (const int*)d_in[17];
    float* out = (float*)d_out;
    float* ws  = (float*)d_ws;

    precompute_kernel<<<181, 256, 0, stream>>>(pe, ve, oe, W_pred, b_pred,
                                               W_bin, b_bin, W_un, W_univ, W_fin,
                                               W_att, b_att, ws);
    fused_kernel<<<MBIN/512, 512, 0, stream>>>(W_att, b_att, b_un, b_univ, b_fin,
                                               pred_ids, var_ids, op_ids, ws, out);
}